// Round 10
// baseline (272.696 us; speedup 1.0000x reference)
//
#include <hip/hip_runtime.h>
#include <hip/hip_bf16.h>
#include <math.h>

#define NN 65536
#define EE 1048576
#define NG 512

// fused splits
#define PH1A_B 256
#define PACK_B 26
#define GB_B   3
#define K1_B   (PH1A_B + PACK_B + GB_B)
#define PH2_B  256
#define GEMM1_B 512
#define K2_B   (PH2_B + GEMM1_B)
#define POOL_B 512

typedef __attribute__((ext_vector_type(8))) short bf16x8;
typedef __attribute__((ext_vector_type(4))) float f32x4;
typedef __attribute__((ext_vector_type(2))) float f32x2;

__device__ __constant__ const float BNS = 0.9999950000374997f; // 1/sqrt(1+1e-5)

// ---------------- bf16 helpers ----------------
__device__ inline float lo_bf(uint u) { union { uint i; float f; } v; v.i = u << 16; return v.f; }
__device__ inline float hi_bf(uint u) { union { uint i; float f; } v; v.i = u & 0xFFFF0000u; return v.f; }
__device__ inline uint f2bf(float f) {
  union { float f; uint i; } v; v.f = f;
  uint r = v.i + 0x7FFFu + ((v.i >> 16) & 1u);  // RTNE
  return r >> 16;
}
__device__ inline uint pack_bf2(float a, float b) { return f2bf(a) | (f2bf(b) << 16); }
// unpack uint4 (8 bf16) into 4 packed f32x2 pairs {elem2j, elem2j+1}
__device__ inline void cvt8p(uint4 v, f32x2* o) {
  o[0] = (f32x2){lo_bf(v.x), hi_bf(v.x)};
  o[1] = (f32x2){lo_bf(v.y), hi_bf(v.y)};
  o[2] = (f32x2){lo_bf(v.z), hi_bf(v.z)};
  o[3] = (f32x2){lo_bf(v.w), hi_bf(v.w)};
}

// ================= phase 1A: per-(block,bucket) counts =================

__device__ void dev_ph1a(int b, const int* __restrict__ ei,
                         int* __restrict__ ph1cnt) {
  __shared__ int lcnt[256];
  int t = threadIdx.x;
  lcnt[t] = 0;
  __syncthreads();
#pragma unroll
  for (int it = 0; it < 16; ++it) {
    int d = ei[EE + b * 4096 + it * 256 + t];
    atomicAdd(&lcnt[d >> 8], 1);
  }
  __syncthreads();
  ph1cnt[t * 256 + b] = lcnt[t];   // bucket-major for the scan
}

// pack W [FIN x FOUT] f32 into MFMA A-fragment layout (bf16)
__device__ void dev_pack(int b,
    const float* __restrict__ Wl1, const float* __restrict__ Wr1,
    const float* __restrict__ Wl2, const float* __restrict__ Wr2,
    const float* __restrict__ Wl3, const float* __restrict__ Wr3,
    ushort* __restrict__ P1l, ushort* __restrict__ P1r,
    ushort* __restrict__ P2l, ushort* __restrict__ P2r,
    ushort* __restrict__ P3l, ushort* __restrict__ P3r) {
  const float* W; ushort* P; int FIN, FOUT, base;
  if (b < 8)       { W = Wl1; P = P1l; FIN = 128; FOUT = 128; base = b; }
  else if (b < 16) { W = Wr1; P = P1r; FIN = 128; FOUT = 128; base = b - 8; }
  else if (b < 20) { W = Wl2; P = P2l; FIN = 128; FOUT = 64;  base = b - 16; }
  else if (b < 24) { W = Wr2; P = P2r; FIN = 128; FOUT = 64;  base = b - 20; }
  else if (b < 25) { W = Wl3; P = P3l; FIN = 64;  FOUT = 32;  base = 0; }
  else             { W = Wr3; P = P3r; FIN = 64;  FOUT = 32;  base = 0; }
  int tid = base * 256 + threadIdx.x;
  int KS = FIN / 32, NF = FOUT / 16;
  if (tid >= NF * KS * 64) return;
  int lane = tid & 63, t = (tid >> 6) % KS, cf = (tid >> 6) / KS;
  int f = cf * 16 + (lane & 15);
  int k0 = t * 32 + (lane >> 4) * 8;
  uint4 v;
  v.x = pack_bf2(W[(k0 + 0) * FOUT + f], W[(k0 + 1) * FOUT + f]);
  v.y = pack_bf2(W[(k0 + 2) * FOUT + f], W[(k0 + 3) * FOUT + f]);
  v.z = pack_bf2(W[(k0 + 4) * FOUT + f], W[(k0 + 5) * FOUT + f]);
  v.w = pack_bf2(W[(k0 + 6) * FOUT + f], W[(k0 + 7) * FOUT + f]);
  ((uint4*)P)[tid] = v;
}

__device__ void dev_gbound(int lb, const int* __restrict__ batch,
                           int* __restrict__ goff) {
  int g = lb * 256 + threadIdx.x;
  if (g > NG) return;
  int lo = 0, hi = NN;
  while (lo < hi) {
    int mid = (lo + hi) >> 1;
    if (batch[mid] < g) lo = mid + 1; else hi = mid;
  }
  goff[g] = lo;
}

__global__ __launch_bounds__(256) void k_ph1a_pack_gbound(
    const int* __restrict__ ei, int* __restrict__ ph1cnt,
    const float* __restrict__ Wl1, const float* __restrict__ Wr1,
    const float* __restrict__ Wl2, const float* __restrict__ Wr2,
    const float* __restrict__ Wl3, const float* __restrict__ Wr3,
    ushort* __restrict__ P1l, ushort* __restrict__ P1r,
    ushort* __restrict__ P2l, ushort* __restrict__ P2r,
    ushort* __restrict__ P3l, ushort* __restrict__ P3r,
    const int* __restrict__ batch, int* __restrict__ goff) {
  int b = blockIdx.x;
  if (b < PH1A_B) dev_ph1a(b, ei, ph1cnt);
  else if (b < PH1A_B + PACK_B)
    dev_pack(b - PH1A_B, Wl1, Wr1, Wl2, Wr2, Wl3, Wr3,
             P1l, P1r, P2l, P2r, P3l, P3r);
  else dev_gbound(b - PH1A_B - PACK_B, batch, goff);
}

// ================= scans =================

__global__ __launch_bounds__(256) void scan1_kernel(const int* __restrict__ cnt,
                                                    int* __restrict__ bsum) {
  __shared__ int ws[4];
  int b = blockIdx.x, t = threadIdx.x;
  int4 v = ((const int4*)(cnt + b * 1024))[t];
  int s = v.x + v.y + v.z + v.w;
#pragma unroll
  for (int d = 1; d < 64; d <<= 1) s += __shfl_xor(s, d);
  if ((t & 63) == 0) ws[t >> 6] = s;
  __syncthreads();
  if (t == 0) bsum[b] = ws[0] + ws[1] + ws[2] + ws[3];
}

__global__ __launch_bounds__(64) void scan2_kernel(const int* __restrict__ bsum,
                                                   int* __restrict__ boff) {
  int t = threadIdx.x;
  int v = bsum[t];
  int s = v;
#pragma unroll
  for (int d = 1; d < 64; d <<= 1) {
    int u = __shfl_up(s, d);
    if (t >= d) s += u;
  }
  boff[t] = s - v;
}

__global__ __launch_bounds__(256) void scan3_kernel(const int* __restrict__ cnt,
                                                    const int* __restrict__ boff,
                                                    int* __restrict__ off) {
  __shared__ int wsum[4];
  int b = blockIdx.x, t = threadIdx.x;
  int base = b * 1024;
  int4 v = ((const int4*)(cnt + base))[t];
  int s = v.x + v.y + v.z + v.w;
  int inc = s;
#pragma unroll
  for (int d = 1; d < 64; d <<= 1) {
    int u = __shfl_up(inc, d);
    if ((t & 63) >= d) inc += u;
  }
  int wave = t >> 6;
  if ((t & 63) == 63) wsum[wave] = inc;
  __syncthreads();
  int wadd = 0;
  for (int wv = 0; wv < wave; ++wv) wadd += wsum[wv];
  int ex = inc - s + wadd + boff[b];
  int4 o;
  o.x = ex; o.y = ex + v.x; o.z = o.y + v.y; o.w = o.z + v.z;
  ((int4*)(off + base))[t] = o;
}

// ================= phase 1B: bucket-scatter (LDS cursors only) =============

__global__ __launch_bounds__(256) void k_ph1b(const int* __restrict__ ei,
                                              const int* __restrict__ ph1off,
                                              uint* __restrict__ ebuf) {
  __shared__ int lcur[256];
  int b = blockIdx.x, t = threadIdx.x;
  lcur[t] = ph1off[t * 256 + b];
  __syncthreads();
#pragma unroll
  for (int it = 0; it < 16; ++it) {
    int e = b * 4096 + it * 256 + t;
    int s = ei[e];
    int d = ei[EE + e];
    int pos = atomicAdd(&lcur[d >> 8], 1);
    ebuf[pos] = (uint)s | ((uint)(d & 255) << 16);
  }
}

// ================= GEMM (packed W fragments) =================

template <int FIN, int FOUT, int TILES, bool F32IN>
__device__ void dev_gemm(int lb, const void* __restrict__ xin,
                         const ushort* __restrict__ Wlp,
                         const ushort* __restrict__ Wrp,
                         ushort* __restrict__ xl, ushort* __restrict__ xr) {
  constexpr int KS = FIN / 32;
  constexpr int NF = FOUT / 16;
  constexpr int FW = (NF < 4) ? NF : 4;
  constexpr int CFW = NF / FW;
  constexpr int NW = 4 / FW;
  const int w = threadIdx.x >> 6, lane = threadIdx.x & 63;
  const int fseg = w % FW, ng = w / FW;
  const int l15 = lane & 15, lhi = lane >> 4;

  bf16x8 wfl[CFW][KS], wfr[CFW][KS];
#pragma unroll
  for (int c = 0; c < CFW; ++c)
#pragma unroll
    for (int t = 0; t < KS; ++t) {
      int idx = ((fseg * CFW + c) * KS + t) * 64 + lane;
      wfl[c][t] = ((const bf16x8*)Wlp)[idx];
      wfr[c][t] = ((const bf16x8*)Wrp)[idx];
    }

  size_t tile0 = ((size_t)lb * NW + ng) * TILES;
  for (int it = 0; it < TILES; ++it) {
    int mb = (int)(tile0 + it) * 16;
    bf16x8 bx[KS];
    if (F32IN) {
      const float* xrow = (const float*)xin + (size_t)(mb + l15) * FIN;
#pragma unroll
      for (int t = 0; t < KS; ++t) {
        float4 a0 = *(const float4*)(xrow + t * 32 + lhi * 8);
        float4 a1 = *(const float4*)(xrow + t * 32 + lhi * 8 + 4);
        uint4 u;
        u.x = pack_bf2(a0.x, a0.y); u.y = pack_bf2(a0.z, a0.w);
        u.z = pack_bf2(a1.x, a1.y); u.w = pack_bf2(a1.z, a1.w);
        bx[t] = *(bf16x8*)&u;
      }
    } else {
      const bf16x8* xrow = (const bf16x8*)((const ushort*)xin + (size_t)(mb + l15) * FIN);
#pragma unroll
      for (int t = 0; t < KS; ++t) bx[t] = xrow[t * 4 + lhi];
    }
    f32x4 accl[CFW], accr[CFW];
#pragma unroll
    for (int c = 0; c < CFW; ++c) {
      accl[c] = (f32x4){0.f, 0.f, 0.f, 0.f};
      accr[c] = (f32x4){0.f, 0.f, 0.f, 0.f};
    }
#pragma unroll
    for (int t = 0; t < KS; ++t)
#pragma unroll
      for (int c = 0; c < CFW; ++c) {
        accl[c] = __builtin_amdgcn_mfma_f32_16x16x32_bf16(wfl[c][t], bx[t], accl[c], 0, 0, 0);
        accr[c] = __builtin_amdgcn_mfma_f32_16x16x32_bf16(wfr[c][t], bx[t], accr[c], 0, 0, 0);
      }
#pragma unroll
    for (int c = 0; c < CFW; ++c) {
      int f0 = (fseg * CFW + c) * 16 + lhi * 4;
      size_t o = (size_t)(mb + l15) * FOUT + f0;
      uint2 vl; vl.x = pack_bf2(accl[c][0], accl[c][1]); vl.y = pack_bf2(accl[c][2], accl[c][3]);
      *(uint2*)(xl + o) = vl;
      uint2 vr; vr.x = pack_bf2(accr[c][0], accr[c][1]); vr.y = pack_bf2(accr[c][2], accr[c][3]);
      *(uint2*)(xr + o) = vr;
    }
  }
}

// ================= phase 2: per-bucket counting sort → CSR + degree perm ====

__device__ void dev_ph2(int k, const int* __restrict__ ph1off,
                        const uint* __restrict__ ebuf,
                        int* __restrict__ csr_off, ushort* __restrict__ csr_src,
                        int* __restrict__ dperm) {
  __shared__ int ccnt[256], coff[256], lcur[256], tmp[256];
  __shared__ int dh[128], dcur[128], dscan[128];
  int t = threadIdx.x;
  int beg = ph1off[k * 256];
  int end = (k == 255) ? EE : ph1off[(k + 1) * 256];
  ccnt[t] = 0;
  lcur[t] = 0;
  if (t < 128) { dh[t] = 0; dcur[t] = 0; }
  __syncthreads();
  for (int e = beg + t; e < end; e += 256) {
    uint u = ebuf[e];
    atomicAdd(&ccnt[(u >> 16) & 255], 1);
  }
  __syncthreads();
  int s = ccnt[t];
  tmp[t] = s;
#pragma unroll
  for (int d = 1; d < 256; d <<= 1) {
    __syncthreads();
    int u = (t >= d) ? tmp[t - d] : 0;
    __syncthreads();
    tmp[t] += u;
  }
  __syncthreads();
  coff[t] = tmp[t] - s;
  csr_off[k * 256 + t] = beg + tmp[t] - s;
  if (k == 255 && t == 0) csr_off[NN] = EE;
  // degree-ranked permutation of the bucket's 256 dsts (balances edge waves)
  int deg = s > 127 ? 127 : s;
  atomicAdd(&dh[deg], 1);
  __syncthreads();
  if (t < 128) dscan[t] = dh[t];
#pragma unroll
  for (int d = 1; d < 128; d <<= 1) {
    __syncthreads();
    int u = (t >= d && t < 128) ? dscan[t - d] : 0;
    __syncthreads();
    if (t < 128) dscan[t] += u;
  }
  __syncthreads();
  int rank = dscan[deg] - dh[deg] + atomicAdd(&dcur[deg], 1);
  dperm[k * 256 + rank] = k * 256 + t;
  // scatter edges into dst-sorted order
  for (int e = beg + t; e < end; e += 256) {
    uint u = ebuf[e];
    int j = (u >> 16) & 255;
    int pos = atomicAdd(&lcur[j], 1);
    csr_src[beg + coff[j] + pos] = (ushort)(u & 0xFFFFu);
  }
}

__global__ __launch_bounds__(256) void k_ph2_gemm1(
    const int* __restrict__ ph1off, const uint* __restrict__ ebuf,
    int* __restrict__ csr_off, ushort* __restrict__ csr_src,
    int* __restrict__ dperm,
    const float* __restrict__ x, const ushort* __restrict__ P1l,
    const ushort* __restrict__ P1r, ushort* __restrict__ xl,
    ushort* __restrict__ xr) {
  int b = blockIdx.x;
  if (b < PH2_B) dev_ph2(b, ph1off, ebuf, csr_off, csr_src, dperm);
  else dev_gemm<128, 128, 8, true>(b - PH2_B, x, P1l, P1r, xl, xr);
}

// ================= pools / gemms (layers 2,3) =================

template <int FOUT>
__device__ void dev_pool(int g, const ushort* __restrict__ h,
                         const int* __restrict__ goff,
                         float* __restrict__ pooled, int colbase) {
  int t = threadIdx.x;
  constexpr int PAIRS = FOUT / 2;
  if (t >= PAIRS) return;
  float a0 = 0.f, a1 = 0.f;
  int b0 = goff[g], b1 = goff[g + 1];
  const uint* h32 = (const uint*)h;
  for (int n = b0; n < b1; ++n) {
    uint v = h32[(size_t)n * PAIRS + t];
    a0 += lo_bf(v);
    a1 += hi_bf(v);
  }
  pooled[g * 256 + colbase + 2 * t] = a0;
  pooled[g * 256 + colbase + 2 * t + 1] = a1;
}

__global__ __launch_bounds__(256) void k_pool1_gemm2(
    const ushort* __restrict__ h, const int* __restrict__ goff,
    float* __restrict__ pooled, const ushort* __restrict__ P2l,
    const ushort* __restrict__ P2r, ushort* __restrict__ xl,
    ushort* __restrict__ xr) {
  int b = blockIdx.x;
  if (b < POOL_B) dev_pool<128>(b, h, goff, pooled, 0);
  else dev_gemm<128, 64, 8, false>(b - POOL_B, h, P2l, P2r, xl, xr);
}

__global__ __launch_bounds__(256) void k_pool2_gemm3(
    const ushort* __restrict__ h, const int* __restrict__ goff,
    float* __restrict__ pooled, const ushort* __restrict__ P3l,
    const ushort* __restrict__ P3r, ushort* __restrict__ xl,
    ushort* __restrict__ xr) {
  int b = blockIdx.x;
  if (b < POOL_B) dev_pool<64>(b, h, goff, pooled, 128);
  else dev_gemm<64, 32, 8, false>(b - POOL_B, h, P3l, P3r, xl, xr);
}

// ================= edge aggregation: CSR 4-wide, packed f32x2 math ==========

template <int FOUT>
__global__ __launch_bounds__(256) void edge_kernel(
    const ushort* __restrict__ xl, const ushort* __restrict__ xr,
    const int* __restrict__ csr_off, const ushort* __restrict__ csr_src,
    const int* __restrict__ dperm,
    const float* __restrict__ a, const float* __restrict__ b,
    const float* __restrict__ gam, const float* __restrict__ bet,
    ushort* __restrict__ hout) {
  constexpr int GROUP = FOUT / 8;   // 16 / 8 / 4
  constexpr int GPB = 256 / GROUP;
  int slot = blockIdx.x * GPB + threadIdx.x / GROUP;
  int lane = threadIdx.x % GROUP;
  int gid = dperm[slot];            // degree-ranked assignment
  const uint4* xl4 = (const uint4*)xl;

  f32x2 xrf[4];
  cvt8p(((const uint4*)xr)[(size_t)gid * GROUP + lane], xrf);
  f32x2 av[4];
  {
    float4 a0 = ((const float4*)a)[lane * 2], a1 = ((const float4*)a)[lane * 2 + 1];
    av[0] = (f32x2){a0.x, a0.y}; av[1] = (f32x2){a0.z, a0.w};
    av[2] = (f32x2){a1.x, a1.y}; av[3] = (f32x2){a1.z, a1.w};
  }

  // self loop seeds state (p = 1)
  f32x2 xs[4];
  cvt8p(xl4[(size_t)gid * GROUP + lane], xs);
  f32x2 q = (f32x2){0.f, 0.f};
#pragma unroll
  for (int j = 0; j < 4; ++j) {
    f32x2 z = xs[j] + xrf[j];
    q += __builtin_elementwise_max(z, z * 0.2f) * av[j];
  }
  float m = q.x + q.y;
#pragma unroll
  for (int wd = GROUP >> 1; wd >= 1; wd >>= 1) m += __shfl_xor(m, wd);
  float den = 1.f;
  f32x2 acc[4];
#pragma unroll
  for (int j = 0; j < 4; ++j) acc[j] = xs[j];

  int beg = csr_off[gid], end = csr_off[gid + 1];
  int i = beg;
  for (; i + 4 <= end; i += 4) {
    int s0 = csr_src[i], s1 = csr_src[i + 1];
    int s2 = csr_src[i + 2], s3 = csr_src[i + 3];
    uint4 v0 = xl4[(size_t)s0 * GROUP + lane];
    uint4 v1 = xl4[(size_t)s1 * GROUP + lane];
    uint4 v2 = xl4[(size_t)s2 * GROUP + lane];
    uint4 v3 = xl4[(size_t)s3 * GROUP + lane];
    f32x2 x0[4], x1[4], x2[4], x3[4];
    cvt8p(v0, x0); cvt8p(v1, x1); cvt8p(v2, x2); cvt8p(v3, x3);
    f32x2 q0 = {0.f, 0.f}, q1 = {0.f, 0.f}, q2 = {0.f, 0.f}, q3 = {0.f, 0.f};
#pragma unroll
    for (int j = 0; j < 4; ++j) {
      f32x2 z0 = x0[j] + xrf[j];
      f32x2 z1 = x1[j] + xrf[j];
      f32x2 z2 = x2[j] + xrf[j];
      f32x2 z3 = x3[j] + xrf[j];
      q0 += __builtin_elementwise_max(z0, z0 * 0.2f) * av[j];
      q1 += __builtin_elementwise_max(z1, z1 * 0.2f) * av[j];
      q2 += __builtin_elementwise_max(z2, z2 * 0.2f) * av[j];
      q3 += __builtin_elementwise_max(z3, z3 * 0.2f) * av[j];
    }
    float sc0 = q0.x + q0.y, sc1 = q1.x + q1.y;
    float sc2 = q2.x + q2.y, sc3 = q3.x + q3.y;
#pragma unroll
    for (int wd = GROUP >> 1; wd >= 1; wd >>= 1) {
      sc0 += __shfl_xor(sc0, wd);
      sc1 += __shfl_xor(sc1, wd);
      sc2 += __shfl_xor(sc2, wd);
      sc3 += __shfl_xor(sc3, wd);
    }
    float m2 = fmaxf(m, fmaxf(fmaxf(sc0, sc1), fmaxf(sc2, sc3)));
    float scale = __expf(m - m2);
    float p0 = __expf(sc0 - m2), p1 = __expf(sc1 - m2);
    float p2 = __expf(sc2 - m2), p3 = __expf(sc3 - m2);
    den = den * scale + p0 + p1 + p2 + p3;
#pragma unroll
    for (int j = 0; j < 4; ++j)
      acc[j] = acc[j] * scale + x0[j] * p0 + x1[j] * p1 + x2[j] * p2 + x3[j] * p3;
    m = m2;
  }
  for (; i < end; ++i) {
    int s0 = csr_src[i];
    uint4 v0 = xl4[(size_t)s0 * GROUP + lane];
    f32x2 x0[4];
    cvt8p(v0, x0);
    f32x2 q0 = {0.f, 0.f};
#pragma unroll
    for (int j = 0; j < 4; ++j) {
      f32x2 z0 = x0[j] + xrf[j];
      q0 += __builtin_elementwise_max(z0, z0 * 0.2f) * av[j];
    }
    float sc0 = q0.x + q0.y;
#pragma unroll
    for (int wd = GROUP >> 1; wd >= 1; wd >>= 1) sc0 += __shfl_xor(sc0, wd);
    float m2 = fmaxf(m, sc0);
    float scale = __expf(m - m2);
    float p0 = __expf(sc0 - m2);
    den = den * scale + p0;
#pragma unroll
    for (int j = 0; j < 4; ++j) acc[j] = acc[j] * scale + x0[j] * p0;
    m = m2;
  }

  float inv = 1.f / den;
  float4 b0 = ((const float4*)b)[lane * 2], b1 = ((const float4*)b)[lane * 2 + 1];
  float4 g0 = ((const float4*)gam)[lane * 2], g1 = ((const float4*)gam)[lane * 2 + 1];
  float4 e0 = ((const float4*)bet)[lane * 2], e1 = ((const float4*)bet)[lane * 2 + 1];
  f32x2 bb[4] = {{b0.x, b0.y}, {b0.z, b0.w}, {b1.x, b1.y}, {b1.z, b1.w}};
  f32x2 gg[4] = {{g0.x, g0.y}, {g0.z, g0.w}, {g1.x, g1.y}, {g1.z, g1.w}};
  f32x2 ee[4] = {{e0.x, e0.y}, {e0.z, e0.w}, {e1.x, e1.y}, {e1.z, e1.w}};
  f32x2 o[4];
#pragma unroll
  for (int j = 0; j < 4; ++j) {
    f32x2 r = acc[j] * inv + bb[j];
    r = __builtin_elementwise_max(r, (f32x2){0.f, 0.f});
    o[j] = r * (gg[j] * BNS) + ee[j];
  }
  uint4 pv;
  pv.x = pack_bf2(o[0].x, o[0].y); pv.y = pack_bf2(o[1].x, o[1].y);
  pv.z = pack_bf2(o[2].x, o[2].y); pv.w = pack_bf2(o[3].x, o[3].y);
  ((uint4*)hout)[(size_t)gid * GROUP + lane] = pv;
}

// ================= MLP head (pool3/pool4 fused in) =================

__global__ __launch_bounds__(128) void mlp_kernel(
    const ushort* __restrict__ h3, const int* __restrict__ goff,
    const float* __restrict__ pooled, const float* __restrict__ W1,
    const float* __restrict__ b1, const float* __restrict__ g5,
    const float* __restrict__ be5, const float* __restrict__ W2,
    const float* __restrict__ b2, float* __restrict__ out) {
  __shared__ float p[256];
  __shared__ float ps[8][16][2];
  __shared__ float hid[128];
  __shared__ float lg[16];
  int g = blockIdx.x, t = threadIdx.x;
  int n0 = goff[g], n1 = goff[g + 1];
  p[t] = pooled[g * 256 + t];
  if (t < 64) p[128 + t] = pooled[g * 256 + 128 + t];
  {
    int sub = t >> 4, pi = t & 15;
    float a0 = 0.f, a1 = 0.f;
    const uint* h32 = (const uint*)h3;
    for (int n = n0 + sub; n < n1; n += 8) {
      uint v = h32[(size_t)n * 16 + pi];
      a0 += lo_bf(v);
      a1 += hi_bf(v);
    }
    ps[sub][pi][0] = a0;
    ps[sub][pi][1] = a1;
  }
  __syncthreads();
  if (t < 16) {
    float s0 = 0.f, s1 = 0.f;
#pragma unroll
    for (int s = 0; s < 8; ++s) { s0 += ps[s][t][0]; s1 += ps[s][t][1]; }
    p[192 + 2 * t] = s0; p[193 + 2 * t] = s1;   // p3
    p[224 + 2 * t] = s0; p[225 + 2 * t] = s1;   // p4 (= p3, reference bug)
  }
  __syncthreads();
  float acc = b1[t];
  for (int k = 0; k < 256; ++k) acc = fmaf(p[k], W1[k * 128 + t], acc);
  acc = fmaxf(acc, 0.f) * (g5[t] * BNS) + be5[t];
  hid[t] = acc;
  __syncthreads();
  if (t < 16) {
    float l = b2[t];
    for (int k = 0; k < 128; ++k) l = fmaf(hid[k], W2[k * 16 + t], l);
    lg[t] = l;
  }
  __syncthreads();
  if (t < 16) {
    float l = lg[t];
    float m = lg[0];
    for (int k = 1; k < 16; ++k) m = fmaxf(m, lg[k]);
    float se = 0.f;
    for (int k = 0; k < 16; ++k) se += __expf(lg[k] - m);
    out[g * 16 + t] = 1.f / (1.f + __expf(-l));       // sigmoid
    out[NG * 16 + g * 16 + t] = l - m - __logf(se);   // log_softmax
  }
}

// ================= launch =================

extern "C" void kernel_launch(void* const* d_in, const int* in_sizes, int n_in,
                              void* d_out, int out_size, void* d_ws, size_t ws_size,
                              hipStream_t stream) {
  const float* x = (const float*)d_in[0];
  const int* ei = (const int*)d_in[1];
  const int* batch = (const int*)d_in[2];
  const float* Wl1 = (const float*)d_in[4];
  const float* Wr1 = (const float*)d_in[5];
  const float* a1 = (const float*)d_in[6];
  const float* b1 = (const float*)d_in[7];
  const float* g1 = (const float*)d_in[8];
  const float* be1 = (const float*)d_in[9];
  const float* Wl2 = (const float*)d_in[10];
  const float* Wr2 = (const float*)d_in[11];
  const float* a2 = (const float*)d_in[12];
  const float* b2 = (const float*)d_in[13];
  const float* g2 = (const float*)d_in[14];
  const float* be2 = (const float*)d_in[15];
  const float* Wl3 = (const float*)d_in[16];
  const float* Wr3 = (const float*)d_in[17];
  const float* a3 = (const float*)d_in[18];
  const float* b3 = (const float*)d_in[19];
  const float* g3 = (const float*)d_in[20];
  const float* be3 = (const float*)d_in[21];
  // layer 4 (d_in[22..27]) is dead in the reference (h4 = h3) — skipped.
  const float* lin1_W = (const float*)d_in[28];
  const float* lin1_b = (const float*)d_in[29];
  const float* g5 = (const float*)d_in[30];
  const float* be5 = (const float*)d_in[31];
  const float* lin2_W = (const float*)d_in[32];
  const float* lin2_b = (const float*)d_in[33];
  float* out = (float*)d_out;

  // workspace carve (16B-aligned chunks)
  char* w = (char*)d_ws;
  ushort* xl = (ushort*)w;   w += (size_t)NN * 128 * 2;  // 16 MB
  ushort* xr = (ushort*)w;   w += (size_t)NN * 128 * 2;  // 16 MB
  ushort* h  = (ushort*)w;   w += (size_t)NN * 128 * 2;  // 16 MB
  uint* ebuf = (uint*)w;     w += (size_t)EE * 4;        // 4 MB
  int* ph1cnt = (int*)w;     w += (size_t)65536 * 4;     // 256 KB
  int* ph1off = (int*)w;     w += (size_t)(65536 + 16) * 4;
  int* csr_off = (int*)w;    w += (size_t)(NN + 4) * 4;
  ushort* csr_src = (ushort*)w; w += (size_t)(EE + 8) * 2;
  int* dperm = (int*)w;      w += (size_t)NN * 4;        // 256 KB
  ushort* P1l = (ushort*)w;  w += 65536;
  ushort* P1r = (ushort*)w;  w += 65536;
  ushort* P2l = (ushort*)w;  w += 65536;
  ushort* P2r = (ushort*)w;  w += 65536;
  ushort* P3l = (ushort*)w;  w += 65536;
  ushort* P3r = (ushort*)w;  w += 65536;
  int* bsum = (int*)w;       w += 64 * 4;
  int* boff = (int*)w;       w += 64 * 4;
  int* goff = (int*)w;       w += (size_t)(NG + 4) * 4;
  float* pooled = (float*)w; w += (size_t)NG * 256 * 4;

  // bucket counts | weight pack | graph bounds
  k_ph1a_pack_gbound<<<K1_B, 256, 0, stream>>>(ei, ph1cnt, Wl1, Wr1, Wl2, Wr2,
                                               Wl3, Wr3, P1l, P1r, P2l, P2r,
                                               P3l, P3r, batch, goff);
  scan1_kernel<<<64, 256, 0, stream>>>(ph1cnt, bsum);
  scan2_kernel<<<1, 64, 0, stream>>>(bsum, boff);
  scan3_kernel<<<64, 256, 0, stream>>>(ph1cnt, boff, ph1off);

  // bucket scatter
  k_ph1b<<<256, 256, 0, stream>>>(ei, ph1off, ebuf);

  // counting sort + degree perm | gemm layer1 (f32 in, packed W)
  k_ph2_gemm1<<<K2_B, 256, 0, stream>>>(ph1off, ebuf, csr_off, csr_src, dperm,
                                        x, P1l, P1r, xl, xr);

  edge_kernel<128><<<NN / 16, 256, 0, stream>>>(xl, xr, csr_off, csr_src,
                                                dperm, a1, b1, g1, be1, h);

  // pool1 | gemm layer2
  k_pool1_gemm2<<<POOL_B + 512, 256, 0, stream>>>(h, goff, pooled, P2l, P2r,
                                                  xl, xr);
  edge_kernel<64><<<NN / 32, 256, 0, stream>>>(xl, xr, csr_off, csr_src,
                                               dperm, a2, b2, g2, be2, h);

  // pool2 | gemm layer3
  k_pool2_gemm3<<<POOL_B + 256, 256, 0, stream>>>(h, goff, pooled, P3l, P3r,
                                                  xl, xr);
  edge_kernel<32><<<NN / 64, 256, 0, stream>>>(xl, xr, csr_off, csr_src,
                                               dperm, a3, b3, g3, be3, h);

  // MLP head (pool3/p4 fused)
  mlp_kernel<<<NG, 128, 0, stream>>>(h, goff, pooled, lin1_W, lin1_b, g5, be5,
                                     lin2_W, lin2_b, out);
}

// Round 11
// 256.028 us; speedup vs baseline: 1.0651x; 1.0651x over previous
//
#include <hip/hip_runtime.h>
#include <hip/hip_bf16.h>
#include <math.h>

#define NN 65536
#define EE 1048576
#define NG 512

// fused splits
#define PH1A_B 256
#define PACK_B 26
#define GB_B   3
#define K1_B   (PH1A_B + PACK_B + GB_B)
#define PH2_B  256
#define GEMM1_B 512
#define K2_B   (PH2_B + GEMM1_B)
#define POOL_B 512

typedef __attribute__((ext_vector_type(8))) short bf16x8;
typedef __attribute__((ext_vector_type(4))) float f32x4;
typedef __attribute__((ext_vector_type(2))) float f32x2;

__device__ __constant__ const float BNS = 0.9999950000374997f; // 1/sqrt(1+1e-5)

// ---------------- bf16 helpers ----------------
__device__ inline float lo_bf(uint u) { union { uint i; float f; } v; v.i = u << 16; return v.f; }
__device__ inline float hi_bf(uint u) { union { uint i; float f; } v; v.i = u & 0xFFFF0000u; return v.f; }
__device__ inline uint f2bf(float f) {
  union { float f; uint i; } v; v.f = f;
  uint r = v.i + 0x7FFFu + ((v.i >> 16) & 1u);  // RTNE
  return r >> 16;
}
__device__ inline uint pack_bf2(float a, float b) { return f2bf(a) | (f2bf(b) << 16); }
// unpack uint4 (8 bf16) into 4 packed f32x2 pairs {elem2j, elem2j+1}
__device__ inline void cvt8p(uint4 v, f32x2* o) {
  o[0] = (f32x2){lo_bf(v.x), hi_bf(v.x)};
  o[1] = (f32x2){lo_bf(v.y), hi_bf(v.y)};
  o[2] = (f32x2){lo_bf(v.z), hi_bf(v.z)};
  o[3] = (f32x2){lo_bf(v.w), hi_bf(v.w)};
}

// ================= phase 1A: per-(block,bucket) counts =================

__device__ void dev_ph1a(int b, const int* __restrict__ ei,
                         int* __restrict__ ph1cnt) {
  __shared__ int lcnt[256];
  int t = threadIdx.x;
  lcnt[t] = 0;
  __syncthreads();
#pragma unroll
  for (int it = 0; it < 16; ++it) {
    int d = ei[EE + b * 4096 + it * 256 + t];
    atomicAdd(&lcnt[d >> 8], 1);
  }
  __syncthreads();
  ph1cnt[t * 256 + b] = lcnt[t];   // bucket-major for the scan
}

// pack W [FIN x FOUT] f32 into MFMA A-fragment layout (bf16)
__device__ void dev_pack(int b,
    const float* __restrict__ Wl1, const float* __restrict__ Wr1,
    const float* __restrict__ Wl2, const float* __restrict__ Wr2,
    const float* __restrict__ Wl3, const float* __restrict__ Wr3,
    ushort* __restrict__ P1l, ushort* __restrict__ P1r,
    ushort* __restrict__ P2l, ushort* __restrict__ P2r,
    ushort* __restrict__ P3l, ushort* __restrict__ P3r) {
  const float* W; ushort* P; int FIN, FOUT, base;
  if (b < 8)       { W = Wl1; P = P1l; FIN = 128; FOUT = 128; base = b; }
  else if (b < 16) { W = Wr1; P = P1r; FIN = 128; FOUT = 128; base = b - 8; }
  else if (b < 20) { W = Wl2; P = P2l; FIN = 128; FOUT = 64;  base = b - 16; }
  else if (b < 24) { W = Wr2; P = P2r; FIN = 128; FOUT = 64;  base = b - 20; }
  else if (b < 25) { W = Wl3; P = P3l; FIN = 64;  FOUT = 32;  base = 0; }
  else             { W = Wr3; P = P3r; FIN = 64;  FOUT = 32;  base = 0; }
  int tid = base * 256 + threadIdx.x;
  int KS = FIN / 32, NF = FOUT / 16;
  if (tid >= NF * KS * 64) return;
  int lane = tid & 63, t = (tid >> 6) % KS, cf = (tid >> 6) / KS;
  int f = cf * 16 + (lane & 15);
  int k0 = t * 32 + (lane >> 4) * 8;
  uint4 v;
  v.x = pack_bf2(W[(k0 + 0) * FOUT + f], W[(k0 + 1) * FOUT + f]);
  v.y = pack_bf2(W[(k0 + 2) * FOUT + f], W[(k0 + 3) * FOUT + f]);
  v.z = pack_bf2(W[(k0 + 4) * FOUT + f], W[(k0 + 5) * FOUT + f]);
  v.w = pack_bf2(W[(k0 + 6) * FOUT + f], W[(k0 + 7) * FOUT + f]);
  ((uint4*)P)[tid] = v;
}

__device__ void dev_gbound(int lb, const int* __restrict__ batch,
                           int* __restrict__ goff) {
  int g = lb * 256 + threadIdx.x;
  if (g > NG) return;
  int lo = 0, hi = NN;
  while (lo < hi) {
    int mid = (lo + hi) >> 1;
    if (batch[mid] < g) lo = mid + 1; else hi = mid;
  }
  goff[g] = lo;
}

__global__ __launch_bounds__(256) void k_ph1a_pack_gbound(
    const int* __restrict__ ei, int* __restrict__ ph1cnt,
    const float* __restrict__ Wl1, const float* __restrict__ Wr1,
    const float* __restrict__ Wl2, const float* __restrict__ Wr2,
    const float* __restrict__ Wl3, const float* __restrict__ Wr3,
    ushort* __restrict__ P1l, ushort* __restrict__ P1r,
    ushort* __restrict__ P2l, ushort* __restrict__ P2r,
    ushort* __restrict__ P3l, ushort* __restrict__ P3r,
    const int* __restrict__ batch, int* __restrict__ goff) {
  int b = blockIdx.x;
  if (b < PH1A_B) dev_ph1a(b, ei, ph1cnt);
  else if (b < PH1A_B + PACK_B)
    dev_pack(b - PH1A_B, Wl1, Wr1, Wl2, Wr2, Wl3, Wr3,
             P1l, P1r, P2l, P2r, P3l, P3r);
  else dev_gbound(b - PH1A_B - PACK_B, batch, goff);
}

// ================= scans =================

__global__ __launch_bounds__(256) void scan1_kernel(const int* __restrict__ cnt,
                                                    int* __restrict__ bsum) {
  __shared__ int ws[4];
  int b = blockIdx.x, t = threadIdx.x;
  int4 v = ((const int4*)(cnt + b * 1024))[t];
  int s = v.x + v.y + v.z + v.w;
#pragma unroll
  for (int d = 1; d < 64; d <<= 1) s += __shfl_xor(s, d);
  if ((t & 63) == 0) ws[t >> 6] = s;
  __syncthreads();
  if (t == 0) bsum[b] = ws[0] + ws[1] + ws[2] + ws[3];
}

__global__ __launch_bounds__(64) void scan2_kernel(const int* __restrict__ bsum,
                                                   int* __restrict__ boff) {
  int t = threadIdx.x;
  int v = bsum[t];
  int s = v;
#pragma unroll
  for (int d = 1; d < 64; d <<= 1) {
    int u = __shfl_up(s, d);
    if (t >= d) s += u;
  }
  boff[t] = s - v;
}

__global__ __launch_bounds__(256) void scan3_kernel(const int* __restrict__ cnt,
                                                    const int* __restrict__ boff,
                                                    int* __restrict__ off) {
  __shared__ int wsum[4];
  int b = blockIdx.x, t = threadIdx.x;
  int base = b * 1024;
  int4 v = ((const int4*)(cnt + base))[t];
  int s = v.x + v.y + v.z + v.w;
  int inc = s;
#pragma unroll
  for (int d = 1; d < 64; d <<= 1) {
    int u = __shfl_up(inc, d);
    if ((t & 63) >= d) inc += u;
  }
  int wave = t >> 6;
  if ((t & 63) == 63) wsum[wave] = inc;
  __syncthreads();
  int wadd = 0;
  for (int wv = 0; wv < wave; ++wv) wadd += wsum[wv];
  int ex = inc - s + wadd + boff[b];
  int4 o;
  o.x = ex; o.y = ex + v.x; o.z = o.y + v.y; o.w = o.z + v.z;
  ((int4*)(off + base))[t] = o;
}

// ================= phase 1B: bucket-scatter (LDS cursors only) =============

__global__ __launch_bounds__(256) void k_ph1b(const int* __restrict__ ei,
                                              const int* __restrict__ ph1off,
                                              uint* __restrict__ ebuf) {
  __shared__ int lcur[256];
  int b = blockIdx.x, t = threadIdx.x;
  lcur[t] = ph1off[t * 256 + b];
  __syncthreads();
#pragma unroll
  for (int it = 0; it < 16; ++it) {
    int e = b * 4096 + it * 256 + t;
    int s = ei[e];
    int d = ei[EE + e];
    int pos = atomicAdd(&lcur[d >> 8], 1);
    ebuf[pos] = (uint)s | ((uint)(d & 255) << 16);
  }
}

// ================= GEMM (packed W fragments) =================

template <int FIN, int FOUT, int TILES, bool F32IN>
__device__ void dev_gemm(int lb, const void* __restrict__ xin,
                         const ushort* __restrict__ Wlp,
                         const ushort* __restrict__ Wrp,
                         ushort* __restrict__ xl, ushort* __restrict__ xr) {
  constexpr int KS = FIN / 32;
  constexpr int NF = FOUT / 16;
  constexpr int FW = (NF < 4) ? NF : 4;
  constexpr int CFW = NF / FW;
  constexpr int NW = 4 / FW;
  const int w = threadIdx.x >> 6, lane = threadIdx.x & 63;
  const int fseg = w % FW, ng = w / FW;
  const int l15 = lane & 15, lhi = lane >> 4;

  bf16x8 wfl[CFW][KS], wfr[CFW][KS];
#pragma unroll
  for (int c = 0; c < CFW; ++c)
#pragma unroll
    for (int t = 0; t < KS; ++t) {
      int idx = ((fseg * CFW + c) * KS + t) * 64 + lane;
      wfl[c][t] = ((const bf16x8*)Wlp)[idx];
      wfr[c][t] = ((const bf16x8*)Wrp)[idx];
    }

  size_t tile0 = ((size_t)lb * NW + ng) * TILES;
  for (int it = 0; it < TILES; ++it) {
    int mb = (int)(tile0 + it) * 16;
    bf16x8 bx[KS];
    if (F32IN) {
      const float* xrow = (const float*)xin + (size_t)(mb + l15) * FIN;
#pragma unroll
      for (int t = 0; t < KS; ++t) {
        float4 a0 = *(const float4*)(xrow + t * 32 + lhi * 8);
        float4 a1 = *(const float4*)(xrow + t * 32 + lhi * 8 + 4);
        uint4 u;
        u.x = pack_bf2(a0.x, a0.y); u.y = pack_bf2(a0.z, a0.w);
        u.z = pack_bf2(a1.x, a1.y); u.w = pack_bf2(a1.z, a1.w);
        bx[t] = *(bf16x8*)&u;
      }
    } else {
      const bf16x8* xrow = (const bf16x8*)((const ushort*)xin + (size_t)(mb + l15) * FIN);
#pragma unroll
      for (int t = 0; t < KS; ++t) bx[t] = xrow[t * 4 + lhi];
    }
    f32x4 accl[CFW], accr[CFW];
#pragma unroll
    for (int c = 0; c < CFW; ++c) {
      accl[c] = (f32x4){0.f, 0.f, 0.f, 0.f};
      accr[c] = (f32x4){0.f, 0.f, 0.f, 0.f};
    }
#pragma unroll
    for (int t = 0; t < KS; ++t)
#pragma unroll
      for (int c = 0; c < CFW; ++c) {
        accl[c] = __builtin_amdgcn_mfma_f32_16x16x32_bf16(wfl[c][t], bx[t], accl[c], 0, 0, 0);
        accr[c] = __builtin_amdgcn_mfma_f32_16x16x32_bf16(wfr[c][t], bx[t], accr[c], 0, 0, 0);
      }
#pragma unroll
    for (int c = 0; c < CFW; ++c) {
      int f0 = (fseg * CFW + c) * 16 + lhi * 4;
      size_t o = (size_t)(mb + l15) * FOUT + f0;
      uint2 vl; vl.x = pack_bf2(accl[c][0], accl[c][1]); vl.y = pack_bf2(accl[c][2], accl[c][3]);
      *(uint2*)(xl + o) = vl;
      uint2 vr; vr.x = pack_bf2(accr[c][0], accr[c][1]); vr.y = pack_bf2(accr[c][2], accr[c][3]);
      *(uint2*)(xr + o) = vr;
    }
  }
}

// ================= phase 2: per-bucket counting sort → CSR =================

__device__ void dev_ph2(int k, const int* __restrict__ ph1off,
                        const uint* __restrict__ ebuf,
                        int* __restrict__ csr_off, ushort* __restrict__ csr_src) {
  __shared__ int ccnt[256], coff[256], lcur[256], tmp[256];
  int t = threadIdx.x;
  int beg = ph1off[k * 256];
  int end = (k == 255) ? EE : ph1off[(k + 1) * 256];
  ccnt[t] = 0;
  lcur[t] = 0;
  __syncthreads();
  for (int e = beg + t; e < end; e += 256) {
    uint u = ebuf[e];
    atomicAdd(&ccnt[(u >> 16) & 255], 1);
  }
  __syncthreads();
  int s = ccnt[t];
  tmp[t] = s;
#pragma unroll
  for (int d = 1; d < 256; d <<= 1) {
    __syncthreads();
    int u = (t >= d) ? tmp[t - d] : 0;
    __syncthreads();
    tmp[t] += u;
  }
  __syncthreads();
  coff[t] = tmp[t] - s;
  csr_off[k * 256 + t] = beg + tmp[t] - s;
  if (k == 255 && t == 0) csr_off[NN] = EE;
  __syncthreads();
  for (int e = beg + t; e < end; e += 256) {
    uint u = ebuf[e];
    int j = (u >> 16) & 255;
    int pos = atomicAdd(&lcur[j], 1);
    csr_src[beg + coff[j] + pos] = (ushort)(u & 0xFFFFu);
  }
}

__global__ __launch_bounds__(256) void k_ph2_gemm1(
    const int* __restrict__ ph1off, const uint* __restrict__ ebuf,
    int* __restrict__ csr_off, ushort* __restrict__ csr_src,
    const float* __restrict__ x, const ushort* __restrict__ P1l,
    const ushort* __restrict__ P1r, ushort* __restrict__ xl,
    ushort* __restrict__ xr) {
  int b = blockIdx.x;
  if (b < PH2_B) dev_ph2(b, ph1off, ebuf, csr_off, csr_src);
  else dev_gemm<128, 128, 8, true>(b - PH2_B, x, P1l, P1r, xl, xr);
}

// ================= pools / gemms (layers 2,3) =================

template <int FOUT>
__device__ void dev_pool(int g, const ushort* __restrict__ h,
                         const int* __restrict__ goff,
                         float* __restrict__ pooled, int colbase) {
  int t = threadIdx.x;
  constexpr int PAIRS = FOUT / 2;
  if (t >= PAIRS) return;
  float a0 = 0.f, a1 = 0.f;
  int b0 = goff[g], b1 = goff[g + 1];
  const uint* h32 = (const uint*)h;
  for (int n = b0; n < b1; ++n) {
    uint v = h32[(size_t)n * PAIRS + t];
    a0 += lo_bf(v);
    a1 += hi_bf(v);
  }
  pooled[g * 256 + colbase + 2 * t] = a0;
  pooled[g * 256 + colbase + 2 * t + 1] = a1;
}

__global__ __launch_bounds__(256) void k_pool1_gemm2(
    const ushort* __restrict__ h, const int* __restrict__ goff,
    float* __restrict__ pooled, const ushort* __restrict__ P2l,
    const ushort* __restrict__ P2r, ushort* __restrict__ xl,
    ushort* __restrict__ xr) {
  int b = blockIdx.x;
  if (b < POOL_B) dev_pool<128>(b, h, goff, pooled, 0);
  else dev_gemm<128, 64, 8, false>(b - POOL_B, h, P2l, P2r, xl, xr);
}

__global__ __launch_bounds__(256) void k_pool2_gemm3(
    const ushort* __restrict__ h, const int* __restrict__ goff,
    float* __restrict__ pooled, const ushort* __restrict__ P3l,
    const ushort* __restrict__ P3r, ushort* __restrict__ xl,
    ushort* __restrict__ xr) {
  int b = blockIdx.x;
  if (b < POOL_B) dev_pool<64>(b, h, goff, pooled, 128);
  else dev_gemm<64, 32, 8, false>(b - POOL_B, h, P3l, P3r, xl, xr);
}

// ================= edge aggregation: pipelined 4-batch, packed f32x2 ========

template <int FOUT>
__global__ __launch_bounds__(256) void edge_kernel(
    const ushort* __restrict__ xl, const ushort* __restrict__ xr,
    const int* __restrict__ csr_off, const ushort* __restrict__ csr_src,
    const float* __restrict__ a, const float* __restrict__ b,
    const float* __restrict__ gam, const float* __restrict__ bet,
    ushort* __restrict__ hout) {
  constexpr int GROUP = FOUT / 8;   // 16 / 8 / 4
  constexpr int GPB = 256 / GROUP;
  int gid = blockIdx.x * GPB + threadIdx.x / GROUP;
  int lane = threadIdx.x % GROUP;
  const uint4* xl4 = (const uint4*)xl;

  f32x2 xrf[4];
  cvt8p(((const uint4*)xr)[(size_t)gid * GROUP + lane], xrf);
  f32x2 av[4];
  {
    float4 a0 = ((const float4*)a)[lane * 2], a1 = ((const float4*)a)[lane * 2 + 1];
    av[0] = (f32x2){a0.x, a0.y}; av[1] = (f32x2){a0.z, a0.w};
    av[2] = (f32x2){a1.x, a1.y}; av[3] = (f32x2){a1.z, a1.w};
  }

  // self loop seeds state (p = 1)
  f32x2 xs[4];
  cvt8p(xl4[(size_t)gid * GROUP + lane], xs);
  f32x2 q = (f32x2){0.f, 0.f};
#pragma unroll
  for (int j = 0; j < 4; ++j) {
    f32x2 z = xs[j] + xrf[j];
    q += __builtin_elementwise_max(z, z * 0.2f) * av[j];
  }
  float m = q.x + q.y;
#pragma unroll
  for (int wd = GROUP >> 1; wd >= 1; wd >>= 1) m += __shfl_xor(m, wd);
  float den = 1.f;
  f32x2 acc[4];
#pragma unroll
  for (int j = 0; j < 4; ++j) acc[j] = xs[j];

  int beg = csr_off[gid], end = csr_off[gid + 1];
  // pipelined batches of 4; tail edges masked via sc=-inf (p=0). csr_src has
  // +8 slack so over-reads are memory-safe; gathered rows are finite bf16.
  uint4 cv0 = {0, 0, 0, 0}, cv1 = cv0, cv2 = cv0, cv3 = cv0;
  if (beg < end) {
    int s0 = csr_src[beg], s1 = csr_src[beg + 1];
    int s2 = csr_src[beg + 2], s3 = csr_src[beg + 3];
    cv0 = xl4[(size_t)s0 * GROUP + lane];
    cv1 = xl4[(size_t)s1 * GROUP + lane];
    cv2 = xl4[(size_t)s2 * GROUP + lane];
    cv3 = xl4[(size_t)s3 * GROUP + lane];
  }
  for (int i = beg; i < end; i += 4) {
    uint4 nv0 = cv0, nv1 = cv1, nv2 = cv2, nv3 = cv3;
    int ip = i + 4;
    if (ip < end) {                      // issue next batch before consuming
      int s0 = csr_src[ip], s1 = csr_src[ip + 1];
      int s2 = csr_src[ip + 2], s3 = csr_src[ip + 3];
      nv0 = xl4[(size_t)s0 * GROUP + lane];
      nv1 = xl4[(size_t)s1 * GROUP + lane];
      nv2 = xl4[(size_t)s2 * GROUP + lane];
      nv3 = xl4[(size_t)s3 * GROUP + lane];
    }
    f32x2 x0[4], x1[4], x2[4], x3[4];
    cvt8p(cv0, x0); cvt8p(cv1, x1); cvt8p(cv2, x2); cvt8p(cv3, x3);
    f32x2 q0 = {0.f, 0.f}, q1 = {0.f, 0.f}, q2 = {0.f, 0.f}, q3 = {0.f, 0.f};
#pragma unroll
    for (int j = 0; j < 4; ++j) {
      f32x2 z0 = x0[j] + xrf[j];
      f32x2 z1 = x1[j] + xrf[j];
      f32x2 z2 = x2[j] + xrf[j];
      f32x2 z3 = x3[j] + xrf[j];
      q0 += __builtin_elementwise_max(z0, z0 * 0.2f) * av[j];
      q1 += __builtin_elementwise_max(z1, z1 * 0.2f) * av[j];
      q2 += __builtin_elementwise_max(z2, z2 * 0.2f) * av[j];
      q3 += __builtin_elementwise_max(z3, z3 * 0.2f) * av[j];
    }
    float sc0 = q0.x + q0.y, sc1 = q1.x + q1.y;
    float sc2 = q2.x + q2.y, sc3 = q3.x + q3.y;
    int rem = end - i;                   // >= 1, group-uniform
    if (rem < 4) {
      if (rem < 2) sc1 = -INFINITY;
      if (rem < 3) sc2 = -INFINITY;
      sc3 = -INFINITY;
    }
#pragma unroll
    for (int wd = GROUP >> 1; wd >= 1; wd >>= 1) {
      sc0 += __shfl_xor(sc0, wd);
      sc1 += __shfl_xor(sc1, wd);
      sc2 += __shfl_xor(sc2, wd);
      sc3 += __shfl_xor(sc3, wd);
    }
    float m2 = fmaxf(m, fmaxf(fmaxf(sc0, sc1), fmaxf(sc2, sc3)));
    float scale = __expf(m - m2);
    float p0 = __expf(sc0 - m2), p1 = __expf(sc1 - m2);
    float p2 = __expf(sc2 - m2), p3 = __expf(sc3 - m2);
    den = den * scale + p0 + p1 + p2 + p3;
#pragma unroll
    for (int j = 0; j < 4; ++j)
      acc[j] = acc[j] * scale + x0[j] * p0 + x1[j] * p1 + x2[j] * p2 + x3[j] * p3;
    m = m2;
    cv0 = nv0; cv1 = nv1; cv2 = nv2; cv3 = nv3;
  }

  float inv = 1.f / den;
  float4 b0 = ((const float4*)b)[lane * 2], b1 = ((const float4*)b)[lane * 2 + 1];
  float4 g0 = ((const float4*)gam)[lane * 2], g1 = ((const float4*)gam)[lane * 2 + 1];
  float4 e0 = ((const float4*)bet)[lane * 2], e1 = ((const float4*)bet)[lane * 2 + 1];
  f32x2 bb[4] = {{b0.x, b0.y}, {b0.z, b0.w}, {b1.x, b1.y}, {b1.z, b1.w}};
  f32x2 gg[4] = {{g0.x, g0.y}, {g0.z, g0.w}, {g1.x, g1.y}, {g1.z, g1.w}};
  f32x2 ee[4] = {{e0.x, e0.y}, {e0.z, e0.w}, {e1.x, e1.y}, {e1.z, e1.w}};
  f32x2 o[4];
#pragma unroll
  for (int j = 0; j < 4; ++j) {
    f32x2 r = acc[j] * inv + bb[j];
    r = __builtin_elementwise_max(r, (f32x2){0.f, 0.f});
    o[j] = r * (gg[j] * BNS) + ee[j];
  }
  uint4 pv;
  pv.x = pack_bf2(o[0].x, o[0].y); pv.y = pack_bf2(o[1].x, o[1].y);
  pv.z = pack_bf2(o[2].x, o[2].y); pv.w = pack_bf2(o[3].x, o[3].y);
  ((uint4*)hout)[(size_t)gid * GROUP + lane] = pv;
}

// ================= MLP head (pool3/pool4 fused in) =================

__global__ __launch_bounds__(128) void mlp_kernel(
    const ushort* __restrict__ h3, const int* __restrict__ goff,
    const float* __restrict__ pooled, const float* __restrict__ W1,
    const float* __restrict__ b1, const float* __restrict__ g5,
    const float* __restrict__ be5, const float* __restrict__ W2,
    const float* __restrict__ b2, float* __restrict__ out) {
  __shared__ float p[256];
  __shared__ float ps[8][16][2];
  __shared__ float hid[128];
  __shared__ float lg[16];
  int g = blockIdx.x, t = threadIdx.x;
  int n0 = goff[g], n1 = goff[g + 1];
  p[t] = pooled[g * 256 + t];
  if (t < 64) p[128 + t] = pooled[g * 256 + 128 + t];
  {
    int sub = t >> 4, pi = t & 15;
    float a0 = 0.f, a1 = 0.f;
    const uint* h32 = (const uint*)h3;
    for (int n = n0 + sub; n < n1; n += 8) {
      uint v = h32[(size_t)n * 16 + pi];
      a0 += lo_bf(v);
      a1 += hi_bf(v);
    }
    ps[sub][pi][0] = a0;
    ps[sub][pi][1] = a1;
  }
  __syncthreads();
  if (t < 16) {
    float s0 = 0.f, s1 = 0.f;
#pragma unroll
    for (int s = 0; s < 8; ++s) { s0 += ps[s][t][0]; s1 += ps[s][t][1]; }
    p[192 + 2 * t] = s0; p[193 + 2 * t] = s1;   // p3
    p[224 + 2 * t] = s0; p[225 + 2 * t] = s1;   // p4 (= p3, reference bug)
  }
  __syncthreads();
  float acc = b1[t];
  for (int k = 0; k < 256; ++k) acc = fmaf(p[k], W1[k * 128 + t], acc);
  acc = fmaxf(acc, 0.f) * (g5[t] * BNS) + be5[t];
  hid[t] = acc;
  __syncthreads();
  if (t < 16) {
    float l = b2[t];
    for (int k = 0; k < 128; ++k) l = fmaf(hid[k], W2[k * 16 + t], l);
    lg[t] = l;
  }
  __syncthreads();
  if (t < 16) {
    float l = lg[t];
    float m = lg[0];
    for (int k = 1; k < 16; ++k) m = fmaxf(m, lg[k]);
    float se = 0.f;
    for (int k = 0; k < 16; ++k) se += __expf(lg[k] - m);
    out[g * 16 + t] = 1.f / (1.f + __expf(-l));       // sigmoid
    out[NG * 16 + g * 16 + t] = l - m - __logf(se);   // log_softmax
  }
}

// ================= launch =================

extern "C" void kernel_launch(void* const* d_in, const int* in_sizes, int n_in,
                              void* d_out, int out_size, void* d_ws, size_t ws_size,
                              hipStream_t stream) {
  const float* x = (const float*)d_in[0];
  const int* ei = (const int*)d_in[1];
  const int* batch = (const int*)d_in[2];
  const float* Wl1 = (const float*)d_in[4];
  const float* Wr1 = (const float*)d_in[5];
  const float* a1 = (const float*)d_in[6];
  const float* b1 = (const float*)d_in[7];
  const float* g1 = (const float*)d_in[8];
  const float* be1 = (const float*)d_in[9];
  const float* Wl2 = (const float*)d_in[10];
  const float* Wr2 = (const float*)d_in[11];
  const float* a2 = (const float*)d_in[12];
  const float* b2 = (const float*)d_in[13];
  const float* g2 = (const float*)d_in[14];
  const float* be2 = (const float*)d_in[15];
  const float* Wl3 = (const float*)d_in[16];
  const float* Wr3 = (const float*)d_in[17];
  const float* a3 = (const float*)d_in[18];
  const float* b3 = (const float*)d_in[19];
  const float* g3 = (const float*)d_in[20];
  const float* be3 = (const float*)d_in[21];
  // layer 4 (d_in[22..27]) is dead in the reference (h4 = h3) — skipped.
  const float* lin1_W = (const float*)d_in[28];
  const float* lin1_b = (const float*)d_in[29];
  const float* g5 = (const float*)d_in[30];
  const float* be5 = (const float*)d_in[31];
  const float* lin2_W = (const float*)d_in[32];
  const float* lin2_b = (const float*)d_in[33];
  float* out = (float*)d_out;

  // workspace carve (16B-aligned chunks)
  char* w = (char*)d_ws;
  ushort* xl = (ushort*)w;   w += (size_t)NN * 128 * 2;  // 16 MB
  ushort* xr = (ushort*)w;   w += (size_t)NN * 128 * 2;  // 16 MB
  ushort* h  = (ushort*)w;   w += (size_t)NN * 128 * 2;  // 16 MB
  uint* ebuf = (uint*)w;     w += (size_t)EE * 4;        // 4 MB
  int* ph1cnt = (int*)w;     w += (size_t)65536 * 4;     // 256 KB
  int* ph1off = (int*)w;     w += (size_t)(65536 + 16) * 4;
  int* csr_off = (int*)w;    w += (size_t)(NN + 4) * 4;
  ushort* csr_src = (ushort*)w; w += (size_t)(EE + 8) * 2;
  ushort* P1l = (ushort*)w;  w += 65536;
  ushort* P1r = (ushort*)w;  w += 65536;
  ushort* P2l = (ushort*)w;  w += 65536;
  ushort* P2r = (ushort*)w;  w += 65536;
  ushort* P3l = (ushort*)w;  w += 65536;
  ushort* P3r = (ushort*)w;  w += 65536;
  int* bsum = (int*)w;       w += 64 * 4;
  int* boff = (int*)w;       w += 64 * 4;
  int* goff = (int*)w;       w += (size_t)(NG + 4) * 4;
  float* pooled = (float*)w; w += (size_t)NG * 256 * 4;

  // bucket counts | weight pack | graph bounds
  k_ph1a_pack_gbound<<<K1_B, 256, 0, stream>>>(ei, ph1cnt, Wl1, Wr1, Wl2, Wr2,
                                               Wl3, Wr3, P1l, P1r, P2l, P2r,
                                               P3l, P3r, batch, goff);
  scan1_kernel<<<64, 256, 0, stream>>>(ph1cnt, bsum);
  scan2_kernel<<<1, 64, 0, stream>>>(bsum, boff);
  scan3_kernel<<<64, 256, 0, stream>>>(ph1cnt, boff, ph1off);

  // bucket scatter
  k_ph1b<<<256, 256, 0, stream>>>(ei, ph1off, ebuf);

  // counting sort | gemm layer1 (f32 in, packed W)
  k_ph2_gemm1<<<K2_B, 256, 0, stream>>>(ph1off, ebuf, csr_off, csr_src,
                                        x, P1l, P1r, xl, xr);

  edge_kernel<128><<<NN / 16, 256, 0, stream>>>(xl, xr, csr_off, csr_src,
                                                a1, b1, g1, be1, h);

  // pool1 | gemm layer2
  k_pool1_gemm2<<<POOL_B + 512, 256, 0, stream>>>(h, goff, pooled, P2l, P2r,
                                                  xl, xr);
  edge_kernel<64><<<NN / 32, 256, 0, stream>>>(xl, xr, csr_off, csr_src,
                                               a2, b2, g2, be2, h);

  // pool2 | gemm layer3
  k_pool2_gemm3<<<POOL_B + 256, 256, 0, stream>>>(h, goff, pooled, P3l, P3r,
                                                  xl, xr);
  edge_kernel<32><<<NN / 64, 256, 0, stream>>>(xl, xr, csr_off, csr_src,
                                               a3, b3, g3, be3, h);

  // MLP head (pool3/p4 fused)
  mlp_kernel<<<NG, 128, 0, stream>>>(h, goff, pooled, lin1_W, lin1_b, g5, be5,
                                     lin2_W, lin2_b, out);
}

// Round 12
// 189.386 us; speedup vs baseline: 1.4399x; 1.3519x over previous
//
#include <hip/hip_runtime.h>
#include <hip/hip_bf16.h>
#include <math.h>

#define NN 65536
#define EE 1048576
#define NG 512

// fused splits
#define PH1A_B 256
#define PACK_B 26
#define GB_B   3
#define K1_B   (PH1A_B + PACK_B + GB_B)
#define PH2_B  256
#define GEMM1_B 512
#define K2_B   (PH2_B + GEMM1_B)
#define POOL_B 512

typedef __attribute__((ext_vector_type(8))) short bf16x8;
typedef __attribute__((ext_vector_type(4))) float f32x4;
typedef __attribute__((ext_vector_type(2))) float f32x2;

__device__ __constant__ const float BNS = 0.9999950000374997f; // 1/sqrt(1+1e-5)

// ---------------- bf16 helpers ----------------
__device__ inline float lo_bf(uint u) { union { uint i; float f; } v; v.i = u << 16; return v.f; }
__device__ inline float hi_bf(uint u) { union { uint i; float f; } v; v.i = u & 0xFFFF0000u; return v.f; }
__device__ inline uint f2bf(float f) {
  union { float f; uint i; } v; v.f = f;
  uint r = v.i + 0x7FFFu + ((v.i >> 16) & 1u);  // RTNE
  return r >> 16;
}
__device__ inline uint pack_bf2(float a, float b) { return f2bf(a) | (f2bf(b) << 16); }
// unpack uint4 (8 bf16) into 4 packed f32x2 pairs {elem2j, elem2j+1}
__device__ inline void cvt8p(uint4 v, f32x2* o) {
  o[0] = (f32x2){lo_bf(v.x), hi_bf(v.x)};
  o[1] = (f32x2){lo_bf(v.y), hi_bf(v.y)};
  o[2] = (f32x2){lo_bf(v.z), hi_bf(v.z)};
  o[3] = (f32x2){lo_bf(v.w), hi_bf(v.w)};
}

// ================= phase 1A: per-(block,bucket) counts =================

__device__ void dev_ph1a(int b, const int* __restrict__ ei,
                         int* __restrict__ ph1cnt) {
  __shared__ int lcnt[256];
  int t = threadIdx.x;
  lcnt[t] = 0;
  __syncthreads();
#pragma unroll
  for (int it = 0; it < 16; ++it) {
    int d = ei[EE + b * 4096 + it * 256 + t];
    atomicAdd(&lcnt[d >> 8], 1);
  }
  __syncthreads();
  ph1cnt[t * 256 + b] = lcnt[t];   // bucket-major for the scan
}

// pack W [FIN x FOUT] f32 into MFMA A-fragment layout (bf16)
__device__ void dev_pack(int b,
    const float* __restrict__ Wl1, const float* __restrict__ Wr1,
    const float* __restrict__ Wl2, const float* __restrict__ Wr2,
    const float* __restrict__ Wl3, const float* __restrict__ Wr3,
    ushort* __restrict__ P1l, ushort* __restrict__ P1r,
    ushort* __restrict__ P2l, ushort* __restrict__ P2r,
    ushort* __restrict__ P3l, ushort* __restrict__ P3r) {
  const float* W; ushort* P; int FIN, FOUT, base;
  if (b < 8)       { W = Wl1; P = P1l; FIN = 128; FOUT = 128; base = b; }
  else if (b < 16) { W = Wr1; P = P1r; FIN = 128; FOUT = 128; base = b - 8; }
  else if (b < 20) { W = Wl2; P = P2l; FIN = 128; FOUT = 64;  base = b - 16; }
  else if (b < 24) { W = Wr2; P = P2r; FIN = 128; FOUT = 64;  base = b - 20; }
  else if (b < 25) { W = Wl3; P = P3l; FIN = 64;  FOUT = 32;  base = 0; }
  else             { W = Wr3; P = P3r; FIN = 64;  FOUT = 32;  base = 0; }
  int tid = base * 256 + threadIdx.x;
  int KS = FIN / 32, NF = FOUT / 16;
  if (tid >= NF * KS * 64) return;
  int lane = tid & 63, t = (tid >> 6) % KS, cf = (tid >> 6) / KS;
  int f = cf * 16 + (lane & 15);
  int k0 = t * 32 + (lane >> 4) * 8;
  uint4 v;
  v.x = pack_bf2(W[(k0 + 0) * FOUT + f], W[(k0 + 1) * FOUT + f]);
  v.y = pack_bf2(W[(k0 + 2) * FOUT + f], W[(k0 + 3) * FOUT + f]);
  v.z = pack_bf2(W[(k0 + 4) * FOUT + f], W[(k0 + 5) * FOUT + f]);
  v.w = pack_bf2(W[(k0 + 6) * FOUT + f], W[(k0 + 7) * FOUT + f]);
  ((uint4*)P)[tid] = v;
}

__device__ void dev_gbound(int lb, const int* __restrict__ batch,
                           int* __restrict__ goff) {
  int g = lb * 256 + threadIdx.x;
  if (g > NG) return;
  int lo = 0, hi = NN;
  while (lo < hi) {
    int mid = (lo + hi) >> 1;
    if (batch[mid] < g) lo = mid + 1; else hi = mid;
  }
  goff[g] = lo;
}

__global__ __launch_bounds__(256) void k_ph1a_pack_gbound(
    const int* __restrict__ ei, int* __restrict__ ph1cnt,
    const float* __restrict__ Wl1, const float* __restrict__ Wr1,
    const float* __restrict__ Wl2, const float* __restrict__ Wr2,
    const float* __restrict__ Wl3, const float* __restrict__ Wr3,
    ushort* __restrict__ P1l, ushort* __restrict__ P1r,
    ushort* __restrict__ P2l, ushort* __restrict__ P2r,
    ushort* __restrict__ P3l, ushort* __restrict__ P3r,
    const int* __restrict__ batch, int* __restrict__ goff) {
  int b = blockIdx.x;
  if (b < PH1A_B) dev_ph1a(b, ei, ph1cnt);
  else if (b < PH1A_B + PACK_B)
    dev_pack(b - PH1A_B, Wl1, Wr1, Wl2, Wr2, Wl3, Wr3,
             P1l, P1r, P2l, P2r, P3l, P3r);
  else dev_gbound(b - PH1A_B - PACK_B, batch, goff);
}

// ================= scans =================

__global__ __launch_bounds__(256) void scan1_kernel(const int* __restrict__ cnt,
                                                    int* __restrict__ bsum) {
  __shared__ int ws[4];
  int b = blockIdx.x, t = threadIdx.x;
  int4 v = ((const int4*)(cnt + b * 1024))[t];
  int s = v.x + v.y + v.z + v.w;
#pragma unroll
  for (int d = 1; d < 64; d <<= 1) s += __shfl_xor(s, d);
  if ((t & 63) == 0) ws[t >> 6] = s;
  __syncthreads();
  if (t == 0) bsum[b] = ws[0] + ws[1] + ws[2] + ws[3];
}

__global__ __launch_bounds__(64) void scan2_kernel(const int* __restrict__ bsum,
                                                   int* __restrict__ boff) {
  int t = threadIdx.x;
  int v = bsum[t];
  int s = v;
#pragma unroll
  for (int d = 1; d < 64; d <<= 1) {
    int u = __shfl_up(s, d);
    if (t >= d) s += u;
  }
  boff[t] = s - v;
}

__global__ __launch_bounds__(256) void scan3_kernel(const int* __restrict__ cnt,
                                                    const int* __restrict__ boff,
                                                    int* __restrict__ off) {
  __shared__ int wsum[4];
  int b = blockIdx.x, t = threadIdx.x;
  int base = b * 1024;
  int4 v = ((const int4*)(cnt + base))[t];
  int s = v.x + v.y + v.z + v.w;
  int inc = s;
#pragma unroll
  for (int d = 1; d < 64; d <<= 1) {
    int u = __shfl_up(inc, d);
    if ((t & 63) >= d) inc += u;
  }
  int wave = t >> 6;
  if ((t & 63) == 63) wsum[wave] = inc;
  __syncthreads();
  int wadd = 0;
  for (int wv = 0; wv < wave; ++wv) wadd += wsum[wv];
  int ex = inc - s + wadd + boff[b];
  int4 o;
  o.x = ex; o.y = ex + v.x; o.z = o.y + v.y; o.w = o.z + v.z;
  ((int4*)(off + base))[t] = o;
}

// ================= phase 1B: bucket-scatter (LDS cursors only) =============

__global__ __launch_bounds__(256) void k_ph1b(const int* __restrict__ ei,
                                              const int* __restrict__ ph1off,
                                              uint* __restrict__ ebuf) {
  __shared__ int lcur[256];
  int b = blockIdx.x, t = threadIdx.x;
  lcur[t] = ph1off[t * 256 + b];
  __syncthreads();
#pragma unroll
  for (int it = 0; it < 16; ++it) {
    int e = b * 4096 + it * 256 + t;
    int s = ei[e];
    int d = ei[EE + e];
    int pos = atomicAdd(&lcur[d >> 8], 1);
    ebuf[pos] = (uint)s | ((uint)(d & 255) << 16);
  }
}

// ================= GEMM (packed W fragments) =================

template <int FIN, int FOUT, int TILES, bool F32IN>
__device__ void dev_gemm(int lb, const void* __restrict__ xin,
                         const ushort* __restrict__ Wlp,
                         const ushort* __restrict__ Wrp,
                         ushort* __restrict__ xl, ushort* __restrict__ xr) {
  constexpr int KS = FIN / 32;
  constexpr int NF = FOUT / 16;
  constexpr int FW = (NF < 4) ? NF : 4;
  constexpr int CFW = NF / FW;
  constexpr int NW = 4 / FW;
  const int w = threadIdx.x >> 6, lane = threadIdx.x & 63;
  const int fseg = w % FW, ng = w / FW;
  const int l15 = lane & 15, lhi = lane >> 4;

  bf16x8 wfl[CFW][KS], wfr[CFW][KS];
#pragma unroll
  for (int c = 0; c < CFW; ++c)
#pragma unroll
    for (int t = 0; t < KS; ++t) {
      int idx = ((fseg * CFW + c) * KS + t) * 64 + lane;
      wfl[c][t] = ((const bf16x8*)Wlp)[idx];
      wfr[c][t] = ((const bf16x8*)Wrp)[idx];
    }

  size_t tile0 = ((size_t)lb * NW + ng) * TILES;
  for (int it = 0; it < TILES; ++it) {
    int mb = (int)(tile0 + it) * 16;
    bf16x8 bx[KS];
    if (F32IN) {
      const float* xrow = (const float*)xin + (size_t)(mb + l15) * FIN;
#pragma unroll
      for (int t = 0; t < KS; ++t) {
        float4 a0 = *(const float4*)(xrow + t * 32 + lhi * 8);
        float4 a1 = *(const float4*)(xrow + t * 32 + lhi * 8 + 4);
        uint4 u;
        u.x = pack_bf2(a0.x, a0.y); u.y = pack_bf2(a0.z, a0.w);
        u.z = pack_bf2(a1.x, a1.y); u.w = pack_bf2(a1.z, a1.w);
        bx[t] = *(bf16x8*)&u;
      }
    } else {
      const bf16x8* xrow = (const bf16x8*)((const ushort*)xin + (size_t)(mb + l15) * FIN);
#pragma unroll
      for (int t = 0; t < KS; ++t) bx[t] = xrow[t * 4 + lhi];
    }
    f32x4 accl[CFW], accr[CFW];
#pragma unroll
    for (int c = 0; c < CFW; ++c) {
      accl[c] = (f32x4){0.f, 0.f, 0.f, 0.f};
      accr[c] = (f32x4){0.f, 0.f, 0.f, 0.f};
    }
#pragma unroll
    for (int t = 0; t < KS; ++t)
#pragma unroll
      for (int c = 0; c < CFW; ++c) {
        accl[c] = __builtin_amdgcn_mfma_f32_16x16x32_bf16(wfl[c][t], bx[t], accl[c], 0, 0, 0);
        accr[c] = __builtin_amdgcn_mfma_f32_16x16x32_bf16(wfr[c][t], bx[t], accr[c], 0, 0, 0);
      }
#pragma unroll
    for (int c = 0; c < CFW; ++c) {
      int f0 = (fseg * CFW + c) * 16 + lhi * 4;
      size_t o = (size_t)(mb + l15) * FOUT + f0;
      uint2 vl; vl.x = pack_bf2(accl[c][0], accl[c][1]); vl.y = pack_bf2(accl[c][2], accl[c][3]);
      *(uint2*)(xl + o) = vl;
      uint2 vr; vr.x = pack_bf2(accr[c][0], accr[c][1]); vr.y = pack_bf2(accr[c][2], accr[c][3]);
      *(uint2*)(xr + o) = vr;
    }
  }
}

// ================= phase 2: per-bucket counting sort → CSR =================

__device__ void dev_ph2(int k, const int* __restrict__ ph1off,
                        const uint* __restrict__ ebuf,
                        int* __restrict__ csr_off, ushort* __restrict__ csr_src) {
  __shared__ int ccnt[256], coff[256], lcur[256], tmp[256];
  int t = threadIdx.x;
  int beg = ph1off[k * 256];
  int end = (k == 255) ? EE : ph1off[(k + 1) * 256];
  ccnt[t] = 0;
  lcur[t] = 0;
  __syncthreads();
  for (int e = beg + t; e < end; e += 256) {
    uint u = ebuf[e];
    atomicAdd(&ccnt[(u >> 16) & 255], 1);
  }
  __syncthreads();
  int s = ccnt[t];
  tmp[t] = s;
#pragma unroll
  for (int d = 1; d < 256; d <<= 1) {
    __syncthreads();
    int u = (t >= d) ? tmp[t - d] : 0;
    __syncthreads();
    tmp[t] += u;
  }
  __syncthreads();
  coff[t] = tmp[t] - s;
  csr_off[k * 256 + t] = beg + tmp[t] - s;
  if (k == 255 && t == 0) csr_off[NN] = EE;
  __syncthreads();
  for (int e = beg + t; e < end; e += 256) {
    uint u = ebuf[e];
    int j = (u >> 16) & 255;
    int pos = atomicAdd(&lcur[j], 1);
    csr_src[beg + coff[j] + pos] = (ushort)(u & 0xFFFFu);
  }
}

__global__ __launch_bounds__(256) void k_ph2_gemm1(
    const int* __restrict__ ph1off, const uint* __restrict__ ebuf,
    int* __restrict__ csr_off, ushort* __restrict__ csr_src,
    const float* __restrict__ x, const ushort* __restrict__ P1l,
    const ushort* __restrict__ P1r, ushort* __restrict__ xl,
    ushort* __restrict__ xr) {
  int b = blockIdx.x;
  if (b < PH2_B) dev_ph2(b, ph1off, ebuf, csr_off, csr_src);
  else dev_gemm<128, 128, 8, true>(b - PH2_B, x, P1l, P1r, xl, xr);
}

// ================= pools (all-wave, LDS reduce) / gemms (layers 2,3) ========

template <int FOUT>
__device__ void dev_pool(int g, const ushort* __restrict__ h,
                         const int* __restrict__ goff,
                         float* __restrict__ pooled, int colbase) {
  constexpr int PAIRS = FOUT / 2;     // 64 / 32
  constexpr int SUBS = 256 / PAIRS;   // 4 / 8
  __shared__ float red[SUBS][PAIRS][2];
  int t = threadIdx.x;
  int pi = t % PAIRS, sub = t / PAIRS;
  int n0 = goff[g], n1 = goff[g + 1];
  float a0 = 0.f, a1 = 0.f;
  const uint* h32 = (const uint*)h;
  for (int n = n0 + sub; n < n1; n += SUBS) {
    uint v = h32[(size_t)n * PAIRS + pi];
    a0 += lo_bf(v);
    a1 += hi_bf(v);
  }
  red[sub][pi][0] = a0;
  red[sub][pi][1] = a1;
  __syncthreads();
  if (sub == 0) {
    float s0 = 0.f, s1 = 0.f;
#pragma unroll
    for (int s = 0; s < SUBS; ++s) { s0 += red[s][pi][0]; s1 += red[s][pi][1]; }
    pooled[g * 256 + colbase + 2 * pi] = s0;
    pooled[g * 256 + colbase + 2 * pi + 1] = s1;
  }
}

__global__ __launch_bounds__(256) void k_pool1_gemm2(
    const ushort* __restrict__ h, const int* __restrict__ goff,
    float* __restrict__ pooled, const ushort* __restrict__ P2l,
    const ushort* __restrict__ P2r, ushort* __restrict__ xl,
    ushort* __restrict__ xr) {
  int b = blockIdx.x;
  if (b < POOL_B) dev_pool<128>(b, h, goff, pooled, 0);
  else dev_gemm<128, 64, 8, false>(b - POOL_B, h, P2l, P2r, xl, xr);
}

__global__ __launch_bounds__(256) void k_pool2_gemm3(
    const ushort* __restrict__ h, const int* __restrict__ goff,
    float* __restrict__ pooled, const ushort* __restrict__ P3l,
    const ushort* __restrict__ P3r, ushort* __restrict__ xl,
    ushort* __restrict__ xr) {
  int b = blockIdx.x;
  if (b < POOL_B) dev_pool<64>(b, h, goff, pooled, 128);
  else dev_gemm<64, 32, 8, false>(b - POOL_B, h, P3l, P3r, xl, xr);
}

// ================= edge aggregation: pipelined 4-batch, packed f32x2 ========

template <int FOUT>
__global__ __launch_bounds__(256) void edge_kernel(
    const ushort* __restrict__ xl, const ushort* __restrict__ xr,
    const int* __restrict__ csr_off, const ushort* __restrict__ csr_src,
    const float* __restrict__ a, const float* __restrict__ b,
    const float* __restrict__ gam, const float* __restrict__ bet,
    ushort* __restrict__ hout) {
  constexpr int GROUP = FOUT / 8;   // 16 / 8 / 4
  constexpr int GPB = 256 / GROUP;
  int gid = blockIdx.x * GPB + threadIdx.x / GROUP;
  int lane = threadIdx.x % GROUP;
  const uint4* xl4 = (const uint4*)xl;

  f32x2 xrf[4];
  cvt8p(((const uint4*)xr)[(size_t)gid * GROUP + lane], xrf);
  f32x2 av[4];
  {
    float4 a0 = ((const float4*)a)[lane * 2], a1 = ((const float4*)a)[lane * 2 + 1];
    av[0] = (f32x2){a0.x, a0.y}; av[1] = (f32x2){a0.z, a0.w};
    av[2] = (f32x2){a1.x, a1.y}; av[3] = (f32x2){a1.z, a1.w};
  }

  // self loop seeds state (p = 1)
  f32x2 xs[4];
  cvt8p(xl4[(size_t)gid * GROUP + lane], xs);
  f32x2 q = (f32x2){0.f, 0.f};
#pragma unroll
  for (int j = 0; j < 4; ++j) {
    f32x2 z = xs[j] + xrf[j];
    q += __builtin_elementwise_max(z, z * 0.2f) * av[j];
  }
  float m = q.x + q.y;
#pragma unroll
  for (int wd = GROUP >> 1; wd >= 1; wd >>= 1) m += __shfl_xor(m, wd);
  float den = 1.f;
  f32x2 acc[4];
#pragma unroll
  for (int j = 0; j < 4; ++j) acc[j] = xs[j];

  int beg = csr_off[gid], end = csr_off[gid + 1];
  // pipelined batches of 4; tail edges masked via sc=-inf (p=0). csr_src has
  // +8 slack so over-reads are memory-safe; gathered rows are finite bf16.
  uint4 cv0 = {0, 0, 0, 0}, cv1 = cv0, cv2 = cv0, cv3 = cv0;
  if (beg < end) {
    int s0 = csr_src[beg], s1 = csr_src[beg + 1];
    int s2 = csr_src[beg + 2], s3 = csr_src[beg + 3];
    cv0 = xl4[(size_t)s0 * GROUP + lane];
    cv1 = xl4[(size_t)s1 * GROUP + lane];
    cv2 = xl4[(size_t)s2 * GROUP + lane];
    cv3 = xl4[(size_t)s3 * GROUP + lane];
  }
  for (int i = beg; i < end; i += 4) {
    uint4 nv0 = cv0, nv1 = cv1, nv2 = cv2, nv3 = cv3;
    int ip = i + 4;
    if (ip < end) {                      // issue next batch before consuming
      int s0 = csr_src[ip], s1 = csr_src[ip + 1];
      int s2 = csr_src[ip + 2], s3 = csr_src[ip + 3];
      nv0 = xl4[(size_t)s0 * GROUP + lane];
      nv1 = xl4[(size_t)s1 * GROUP + lane];
      nv2 = xl4[(size_t)s2 * GROUP + lane];
      nv3 = xl4[(size_t)s3 * GROUP + lane];
    }
    f32x2 x0[4], x1[4], x2[4], x3[4];
    cvt8p(cv0, x0); cvt8p(cv1, x1); cvt8p(cv2, x2); cvt8p(cv3, x3);
    f32x2 q0 = {0.f, 0.f}, q1 = {0.f, 0.f}, q2 = {0.f, 0.f}, q3 = {0.f, 0.f};
#pragma unroll
    for (int j = 0; j < 4; ++j) {
      f32x2 z0 = x0[j] + xrf[j];
      f32x2 z1 = x1[j] + xrf[j];
      f32x2 z2 = x2[j] + xrf[j];
      f32x2 z3 = x3[j] + xrf[j];
      q0 += __builtin_elementwise_max(z0, z0 * 0.2f) * av[j];
      q1 += __builtin_elementwise_max(z1, z1 * 0.2f) * av[j];
      q2 += __builtin_elementwise_max(z2, z2 * 0.2f) * av[j];
      q3 += __builtin_elementwise_max(z3, z3 * 0.2f) * av[j];
    }
    float sc0 = q0.x + q0.y, sc1 = q1.x + q1.y;
    float sc2 = q2.x + q2.y, sc3 = q3.x + q3.y;
    int rem = end - i;                   // >= 1, group-uniform
    if (rem < 4) {
      if (rem < 2) sc1 = -INFINITY;
      if (rem < 3) sc2 = -INFINITY;
      sc3 = -INFINITY;
    }
#pragma unroll
    for (int wd = GROUP >> 1; wd >= 1; wd >>= 1) {
      sc0 += __shfl_xor(sc0, wd);
      sc1 += __shfl_xor(sc1, wd);
      sc2 += __shfl_xor(sc2, wd);
      sc3 += __shfl_xor(sc3, wd);
    }
    float m2 = fmaxf(m, fmaxf(fmaxf(sc0, sc1), fmaxf(sc2, sc3)));
    float scale = __expf(m - m2);
    float p0 = __expf(sc0 - m2), p1 = __expf(sc1 - m2);
    float p2 = __expf(sc2 - m2), p3 = __expf(sc3 - m2);
    den = den * scale + p0 + p1 + p2 + p3;
#pragma unroll
    for (int j = 0; j < 4; ++j)
      acc[j] = acc[j] * scale + x0[j] * p0 + x1[j] * p1 + x2[j] * p2 + x3[j] * p3;
    m = m2;
    cv0 = nv0; cv1 = nv1; cv2 = nv2; cv3 = nv3;
  }

  float inv = 1.f / den;
  float4 b0 = ((const float4*)b)[lane * 2], b1 = ((const float4*)b)[lane * 2 + 1];
  float4 g0 = ((const float4*)gam)[lane * 2], g1 = ((const float4*)gam)[lane * 2 + 1];
  float4 e0 = ((const float4*)bet)[lane * 2], e1 = ((const float4*)bet)[lane * 2 + 1];
  f32x2 bb[4] = {{b0.x, b0.y}, {b0.z, b0.w}, {b1.x, b1.y}, {b1.z, b1.w}};
  f32x2 gg[4] = {{g0.x, g0.y}, {g0.z, g0.w}, {g1.x, g1.y}, {g1.z, g1.w}};
  f32x2 ee[4] = {{e0.x, e0.y}, {e0.z, e0.w}, {e1.x, e1.y}, {e1.z, e1.w}};
  f32x2 o[4];
#pragma unroll
  for (int j = 0; j < 4; ++j) {
    f32x2 r = acc[j] * inv + bb[j];
    r = __builtin_elementwise_max(r, (f32x2){0.f, 0.f});
    o[j] = r * (gg[j] * BNS) + ee[j];
  }
  uint4 pv;
  pv.x = pack_bf2(o[0].x, o[0].y); pv.y = pack_bf2(o[1].x, o[1].y);
  pv.z = pack_bf2(o[2].x, o[2].y); pv.w = pack_bf2(o[3].x, o[3].y);
  ((uint4*)hout)[(size_t)gid * GROUP + lane] = pv;
}

// ================= MLP head (pool3/pool4 fused in) =================

__global__ __launch_bounds__(128) void mlp_kernel(
    const ushort* __restrict__ h3, const int* __restrict__ goff,
    const float* __restrict__ pooled, const float* __restrict__ W1,
    const float* __restrict__ b1, const float* __restrict__ g5,
    const float* __restrict__ be5, const float* __restrict__ W2,
    const float* __restrict__ b2, float* __restrict__ out) {
  __shared__ float p[256];
  __shared__ float ps[8][16][2];
  __shared__ float hid[128];
  __shared__ float lg[16];
  int g = blockIdx.x, t = threadIdx.x;
  int n0 = goff[g], n1 = goff[g + 1];
  p[t] = pooled[g * 256 + t];
  if (t < 64) p[128 + t] = pooled[g * 256 + 128 + t];
  {
    int sub = t >> 4, pi = t & 15;
    float a0 = 0.f, a1 = 0.f;
    const uint* h32 = (const uint*)h3;
    for (int n = n0 + sub; n < n1; n += 8) {
      uint v = h32[(size_t)n * 16 + pi];
      a0 += lo_bf(v);
      a1 += hi_bf(v);
    }
    ps[sub][pi][0] = a0;
    ps[sub][pi][1] = a1;
  }
  __syncthreads();
  if (t < 16) {
    float s0 = 0.f, s1 = 0.f;
#pragma unroll
    for (int s = 0; s < 8; ++s) { s0 += ps[s][t][0]; s1 += ps[s][t][1]; }
    p[192 + 2 * t] = s0; p[193 + 2 * t] = s1;   // p3
    p[224 + 2 * t] = s0; p[225 + 2 * t] = s1;   // p4 (= p3, reference bug)
  }
  __syncthreads();
  float acc = b1[t];
  for (int k = 0; k < 256; ++k) acc = fmaf(p[k], W1[k * 128 + t], acc);
  acc = fmaxf(acc, 0.f) * (g5[t] * BNS) + be5[t];
  hid[t] = acc;
  __syncthreads();
  if (t < 16) {
    float l = b2[t];
    for (int k = 0; k < 128; ++k) l = fmaf(hid[k], W2[k * 16 + t], l);
    lg[t] = l;
  }
  __syncthreads();
  if (t < 16) {
    float l = lg[t];
    float m = lg[0];
    for (int k = 1; k < 16; ++k) m = fmaxf(m, lg[k]);
    float se = 0.f;
    for (int k = 0; k < 16; ++k) se += __expf(lg[k] - m);
    out[g * 16 + t] = 1.f / (1.f + __expf(-l));       // sigmoid
    out[NG * 16 + g * 16 + t] = l - m - __logf(se);   // log_softmax
  }
}

// ================= launch =================

extern "C" void kernel_launch(void* const* d_in, const int* in_sizes, int n_in,
                              void* d_out, int out_size, void* d_ws, size_t ws_size,
                              hipStream_t stream) {
  const float* x = (const float*)d_in[0];
  const int* ei = (const int*)d_in[1];
  const int* batch = (const int*)d_in[2];
  const float* Wl1 = (const float*)d_in[4];
  const float* Wr1 = (const float*)d_in[5];
  const float* a1 = (const float*)d_in[6];
  const float* b1 = (const float*)d_in[7];
  const float* g1 = (const float*)d_in[8];
  const float* be1 = (const float*)d_in[9];
  const float* Wl2 = (const float*)d_in[10];
  const float* Wr2 = (const float*)d_in[11];
  const float* a2 = (const float*)d_in[12];
  const float* b2 = (const float*)d_in[13];
  const float* g2 = (const float*)d_in[14];
  const float* be2 = (const float*)d_in[15];
  const float* Wl3 = (const float*)d_in[16];
  const float* Wr3 = (const float*)d_in[17];
  const float* a3 = (const float*)d_in[18];
  const float* b3 = (const float*)d_in[19];
  const float* g3 = (const float*)d_in[20];
  const float* be3 = (const float*)d_in[21];
  // layer 4 (d_in[22..27]) is dead in the reference (h4 = h3) — skipped.
  const float* lin1_W = (const float*)d_in[28];
  const float* lin1_b = (const float*)d_in[29];
  const float* g5 = (const float*)d_in[30];
  const float* be5 = (const float*)d_in[31];
  const float* lin2_W = (const float*)d_in[32];
  const float* lin2_b = (const float*)d_in[33];
  float* out = (float*)d_out;

  // workspace carve (16B-aligned chunks)
  char* w = (char*)d_ws;
  ushort* xl = (ushort*)w;   w += (size_t)NN * 128 * 2;  // 16 MB
  ushort* xr = (ushort*)w;   w += (size_t)NN * 128 * 2;  // 16 MB
  ushort* h  = (ushort*)w;   w += (size_t)NN * 128 * 2;  // 16 MB
  uint* ebuf = (uint*)w;     w += (size_t)EE * 4;        // 4 MB
  int* ph1cnt = (int*)w;     w += (size_t)65536 * 4;     // 256 KB
  int* ph1off = (int*)w;     w += (size_t)(65536 + 16) * 4;
  int* csr_off = (int*)w;    w += (size_t)(NN + 4) * 4;
  ushort* csr_src = (ushort*)w; w += (size_t)(EE + 8) * 2;
  ushort* P1l = (ushort*)w;  w += 65536;
  ushort* P1r = (ushort*)w;  w += 65536;
  ushort* P2l = (ushort*)w;  w += 65536;
  ushort* P2r = (ushort*)w;  w += 65536;
  ushort* P3l = (ushort*)w;  w += 65536;
  ushort* P3r = (ushort*)w;  w += 65536;
  int* bsum = (int*)w;       w += 64 * 4;
  int* boff = (int*)w;       w += 64 * 4;
  int* goff = (int*)w;       w += (size_t)(NG + 4) * 4;
  float* pooled = (float*)w; w += (size_t)NG * 256 * 4;

  // bucket counts | weight pack | graph bounds
  k_ph1a_pack_gbound<<<K1_B, 256, 0, stream>>>(ei, ph1cnt, Wl1, Wr1, Wl2, Wr2,
                                               Wl3, Wr3, P1l, P1r, P2l, P2r,
                                               P3l, P3r, batch, goff);
  scan1_kernel<<<64, 256, 0, stream>>>(ph1cnt, bsum);
  scan2_kernel<<<1, 64, 0, stream>>>(bsum, boff);
  scan3_kernel<<<64, 256, 0, stream>>>(ph1cnt, boff, ph1off);

  // bucket scatter
  k_ph1b<<<256, 256, 0, stream>>>(ei, ph1off, ebuf);

  // counting sort | gemm layer1 (f32 in, packed W)
  k_ph2_gemm1<<<K2_B, 256, 0, stream>>>(ph1off, ebuf, csr_off, csr_src,
                                        x, P1l, P1r, xl, xr);

  edge_kernel<128><<<NN / 16, 256, 0, stream>>>(xl, xr, csr_off, csr_src,
                                                a1, b1, g1, be1, h);

  // pool1 | gemm layer2
  k_pool1_gemm2<<<POOL_B + 512, 256, 0, stream>>>(h, goff, pooled, P2l, P2r,
                                                  xl, xr);
  edge_kernel<64><<<NN / 32, 256, 0, stream>>>(xl, xr, csr_off, csr_src,
                                               a2, b2, g2, be2, h);

  // pool2 | gemm layer3
  k_pool2_gemm3<<<POOL_B + 256, 256, 0, stream>>>(h, goff, pooled, P3l, P3r,
                                                  xl, xr);
  edge_kernel<32><<<NN / 64, 256, 0, stream>>>(xl, xr, csr_off, csr_src,
                                               a3, b3, g3, be3, h);

  // MLP head (pool3/p4 fused)
  mlp_kernel<<<NG, 128, 0, stream>>>(h, goff, pooled, lin1_W, lin1_b, g5, be5,
                                     lin2_W, lin2_b, out);
}

// Round 13
// 187.251 us; speedup vs baseline: 1.4563x; 1.0114x over previous
//
#include <hip/hip_runtime.h>
#include <hip/hip_bf16.h>
#include <math.h>

#define NN 65536
#define EE 1048576
#define NG 512

// fused splits
#define PH1A_B 256
#define PACK_B 26
#define GB_B   3
#define K1_B   (PH1A_B + PACK_B + GB_B)
#define PH2_B  256
#define GEMM1_B 512
#define K2_B   (PH2_B + GEMM1_B)
#define POOL_B 512

typedef __attribute__((ext_vector_type(8))) short bf16x8;
typedef __attribute__((ext_vector_type(4))) float f32x4;
typedef __attribute__((ext_vector_type(2))) float f32x2;

__device__ __constant__ const float BNS = 0.9999950000374997f; // 1/sqrt(1+1e-5)

// ---------------- bf16 helpers ----------------
__device__ inline float lo_bf(uint u) { union { uint i; float f; } v; v.i = u << 16; return v.f; }
__device__ inline float hi_bf(uint u) { union { uint i; float f; } v; v.i = u & 0xFFFF0000u; return v.f; }
__device__ inline uint f2bf(float f) {
  union { float f; uint i; } v; v.f = f;
  uint r = v.i + 0x7FFFu + ((v.i >> 16) & 1u);  // RTNE
  return r >> 16;
}
__device__ inline uint pack_bf2(float a, float b) { return f2bf(a) | (f2bf(b) << 16); }
// unpack uint4 (8 bf16) into 4 packed f32x2 pairs {elem2j, elem2j+1}
__device__ inline void cvt8p(uint4 v, f32x2* o) {
  o[0] = (f32x2){lo_bf(v.x), hi_bf(v.x)};
  o[1] = (f32x2){lo_bf(v.y), hi_bf(v.y)};
  o[2] = (f32x2){lo_bf(v.z), hi_bf(v.z)};
  o[3] = (f32x2){lo_bf(v.w), hi_bf(v.w)};
}

// ================= phase 1A: per-(block,bucket) counts =================

__device__ void dev_ph1a(int b, const int* __restrict__ ei,
                         int* __restrict__ ph1cnt) {
  __shared__ int lcnt[256];
  int t = threadIdx.x;
  lcnt[t] = 0;
  __syncthreads();
  const int4* dbase = (const int4*)(ei + EE) + b * 1024;
#pragma unroll
  for (int it = 0; it < 4; ++it) {
    int4 d4 = dbase[it * 256 + t];
    atomicAdd(&lcnt[d4.x >> 8], 1);
    atomicAdd(&lcnt[d4.y >> 8], 1);
    atomicAdd(&lcnt[d4.z >> 8], 1);
    atomicAdd(&lcnt[d4.w >> 8], 1);
  }
  __syncthreads();
  ph1cnt[t * 256 + b] = lcnt[t];   // bucket-major for the scan
}

// pack W [FIN x FOUT] f32 into MFMA A-fragment layout (bf16)
__device__ void dev_pack(int b,
    const float* __restrict__ Wl1, const float* __restrict__ Wr1,
    const float* __restrict__ Wl2, const float* __restrict__ Wr2,
    const float* __restrict__ Wl3, const float* __restrict__ Wr3,
    ushort* __restrict__ P1l, ushort* __restrict__ P1r,
    ushort* __restrict__ P2l, ushort* __restrict__ P2r,
    ushort* __restrict__ P3l, ushort* __restrict__ P3r) {
  const float* W; ushort* P; int FIN, FOUT, base;
  if (b < 8)       { W = Wl1; P = P1l; FIN = 128; FOUT = 128; base = b; }
  else if (b < 16) { W = Wr1; P = P1r; FIN = 128; FOUT = 128; base = b - 8; }
  else if (b < 20) { W = Wl2; P = P2l; FIN = 128; FOUT = 64;  base = b - 16; }
  else if (b < 24) { W = Wr2; P = P2r; FIN = 128; FOUT = 64;  base = b - 20; }
  else if (b < 25) { W = Wl3; P = P3l; FIN = 64;  FOUT = 32;  base = 0; }
  else             { W = Wr3; P = P3r; FIN = 64;  FOUT = 32;  base = 0; }
  int tid = base * 256 + threadIdx.x;
  int KS = FIN / 32, NF = FOUT / 16;
  if (tid >= NF * KS * 64) return;
  int lane = tid & 63, t = (tid >> 6) % KS, cf = (tid >> 6) / KS;
  int f = cf * 16 + (lane & 15);
  int k0 = t * 32 + (lane >> 4) * 8;
  uint4 v;
  v.x = pack_bf2(W[(k0 + 0) * FOUT + f], W[(k0 + 1) * FOUT + f]);
  v.y = pack_bf2(W[(k0 + 2) * FOUT + f], W[(k0 + 3) * FOUT + f]);
  v.z = pack_bf2(W[(k0 + 4) * FOUT + f], W[(k0 + 5) * FOUT + f]);
  v.w = pack_bf2(W[(k0 + 6) * FOUT + f], W[(k0 + 7) * FOUT + f]);
  ((uint4*)P)[tid] = v;
}

__device__ void dev_gbound(int lb, const int* __restrict__ batch,
                           int* __restrict__ goff) {
  int g = lb * 256 + threadIdx.x;
  if (g > NG) return;
  int lo = 0, hi = NN;
  while (lo < hi) {
    int mid = (lo + hi) >> 1;
    if (batch[mid] < g) lo = mid + 1; else hi = mid;
  }
  goff[g] = lo;
}

__global__ __launch_bounds__(256) void k_ph1a_pack_gbound(
    const int* __restrict__ ei, int* __restrict__ ph1cnt,
    const float* __restrict__ Wl1, const float* __restrict__ Wr1,
    const float* __restrict__ Wl2, const float* __restrict__ Wr2,
    const float* __restrict__ Wl3, const float* __restrict__ Wr3,
    ushort* __restrict__ P1l, ushort* __restrict__ P1r,
    ushort* __restrict__ P2l, ushort* __restrict__ P2r,
    ushort* __restrict__ P3l, ushort* __restrict__ P3r,
    const int* __restrict__ batch, int* __restrict__ goff) {
  int b = blockIdx.x;
  if (b < PH1A_B) dev_ph1a(b, ei, ph1cnt);
  else if (b < PH1A_B + PACK_B)
    dev_pack(b - PH1A_B, Wl1, Wr1, Wl2, Wr2, Wl3, Wr3,
             P1l, P1r, P2l, P2r, P3l, P3r);
  else dev_gbound(b - PH1A_B - PACK_B, batch, goff);
}

// ================= scans =================

__global__ __launch_bounds__(256) void scan1_kernel(const int* __restrict__ cnt,
                                                    int* __restrict__ bsum) {
  __shared__ int ws[4];
  int b = blockIdx.x, t = threadIdx.x;
  int4 v = ((const int4*)(cnt + b * 1024))[t];
  int s = v.x + v.y + v.z + v.w;
#pragma unroll
  for (int d = 1; d < 64; d <<= 1) s += __shfl_xor(s, d);
  if ((t & 63) == 0) ws[t >> 6] = s;
  __syncthreads();
  if (t == 0) bsum[b] = ws[0] + ws[1] + ws[2] + ws[3];
}

__global__ __launch_bounds__(64) void scan2_kernel(const int* __restrict__ bsum,
                                                   int* __restrict__ boff) {
  int t = threadIdx.x;
  int v = bsum[t];
  int s = v;
#pragma unroll
  for (int d = 1; d < 64; d <<= 1) {
    int u = __shfl_up(s, d);
    if (t >= d) s += u;
  }
  boff[t] = s - v;
}

__global__ __launch_bounds__(256) void scan3_kernel(const int* __restrict__ cnt,
                                                    const int* __restrict__ boff,
                                                    int* __restrict__ off) {
  __shared__ int wsum[4];
  int b = blockIdx.x, t = threadIdx.x;
  int base = b * 1024;
  int4 v = ((const int4*)(cnt + base))[t];
  int s = v.x + v.y + v.z + v.w;
  int inc = s;
#pragma unroll
  for (int d = 1; d < 64; d <<= 1) {
    int u = __shfl_up(inc, d);
    if ((t & 63) >= d) inc += u;
  }
  int wave = t >> 6;
  if ((t & 63) == 63) wsum[wave] = inc;
  __syncthreads();
  int wadd = 0;
  for (int wv = 0; wv < wave; ++wv) wadd += wsum[wv];
  int ex = inc - s + wadd + boff[b];
  int4 o;
  o.x = ex; o.y = ex + v.x; o.z = o.y + v.y; o.w = o.z + v.z;
  ((int4*)(off + base))[t] = o;
}

// ================= phase 1B: bucket-scatter (LDS cursors only) =============

__global__ __launch_bounds__(256) void k_ph1b(const int* __restrict__ ei,
                                              const int* __restrict__ ph1off,
                                              uint* __restrict__ ebuf) {
  __shared__ int lcur[256];
  int b = blockIdx.x, t = threadIdx.x;
  lcur[t] = ph1off[t * 256 + b];
  __syncthreads();
  const int4* sbase = (const int4*)ei + b * 1024;
  const int4* dbase = (const int4*)(ei + EE) + b * 1024;
#pragma unroll
  for (int it = 0; it < 4; ++it) {
    int4 s4 = sbase[it * 256 + t];
    int4 d4 = dbase[it * 256 + t];
    int p0 = atomicAdd(&lcur[d4.x >> 8], 1);
    ebuf[p0] = (uint)s4.x | ((uint)(d4.x & 255) << 16);
    int p1 = atomicAdd(&lcur[d4.y >> 8], 1);
    ebuf[p1] = (uint)s4.y | ((uint)(d4.y & 255) << 16);
    int p2 = atomicAdd(&lcur[d4.z >> 8], 1);
    ebuf[p2] = (uint)s4.z | ((uint)(d4.z & 255) << 16);
    int p3 = atomicAdd(&lcur[d4.w >> 8], 1);
    ebuf[p3] = (uint)s4.w | ((uint)(d4.w & 255) << 16);
  }
}

// ================= GEMM (packed W fragments) =================

template <int FIN, int FOUT, int TILES, bool F32IN>
__device__ void dev_gemm(int lb, const void* __restrict__ xin,
                         const ushort* __restrict__ Wlp,
                         const ushort* __restrict__ Wrp,
                         ushort* __restrict__ xl, ushort* __restrict__ xr) {
  constexpr int KS = FIN / 32;
  constexpr int NF = FOUT / 16;
  constexpr int FW = (NF < 4) ? NF : 4;
  constexpr int CFW = NF / FW;
  constexpr int NW = 4 / FW;
  const int w = threadIdx.x >> 6, lane = threadIdx.x & 63;
  const int fseg = w % FW, ng = w / FW;
  const int l15 = lane & 15, lhi = lane >> 4;

  bf16x8 wfl[CFW][KS], wfr[CFW][KS];
#pragma unroll
  for (int c = 0; c < CFW; ++c)
#pragma unroll
    for (int t = 0; t < KS; ++t) {
      int idx = ((fseg * CFW + c) * KS + t) * 64 + lane;
      wfl[c][t] = ((const bf16x8*)Wlp)[idx];
      wfr[c][t] = ((const bf16x8*)Wrp)[idx];
    }

  size_t tile0 = ((size_t)lb * NW + ng) * TILES;
  for (int it = 0; it < TILES; ++it) {
    int mb = (int)(tile0 + it) * 16;
    bf16x8 bx[KS];
    if (F32IN) {
      const float* xrow = (const float*)xin + (size_t)(mb + l15) * FIN;
#pragma unroll
      for (int t = 0; t < KS; ++t) {
        float4 a0 = *(const float4*)(xrow + t * 32 + lhi * 8);
        float4 a1 = *(const float4*)(xrow + t * 32 + lhi * 8 + 4);
        uint4 u;
        u.x = pack_bf2(a0.x, a0.y); u.y = pack_bf2(a0.z, a0.w);
        u.z = pack_bf2(a1.x, a1.y); u.w = pack_bf2(a1.z, a1.w);
        bx[t] = *(bf16x8*)&u;
      }
    } else {
      const bf16x8* xrow = (const bf16x8*)((const ushort*)xin + (size_t)(mb + l15) * FIN);
#pragma unroll
      for (int t = 0; t < KS; ++t) bx[t] = xrow[t * 4 + lhi];
    }
    f32x4 accl[CFW], accr[CFW];
#pragma unroll
    for (int c = 0; c < CFW; ++c) {
      accl[c] = (f32x4){0.f, 0.f, 0.f, 0.f};
      accr[c] = (f32x4){0.f, 0.f, 0.f, 0.f};
    }
#pragma unroll
    for (int t = 0; t < KS; ++t)
#pragma unroll
      for (int c = 0; c < CFW; ++c) {
        accl[c] = __builtin_amdgcn_mfma_f32_16x16x32_bf16(wfl[c][t], bx[t], accl[c], 0, 0, 0);
        accr[c] = __builtin_amdgcn_mfma_f32_16x16x32_bf16(wfr[c][t], bx[t], accr[c], 0, 0, 0);
      }
#pragma unroll
    for (int c = 0; c < CFW; ++c) {
      int f0 = (fseg * CFW + c) * 16 + lhi * 4;
      size_t o = (size_t)(mb + l15) * FOUT + f0;
      uint2 vl; vl.x = pack_bf2(accl[c][0], accl[c][1]); vl.y = pack_bf2(accl[c][2], accl[c][3]);
      *(uint2*)(xl + o) = vl;
      uint2 vr; vr.x = pack_bf2(accr[c][0], accr[c][1]); vr.y = pack_bf2(accr[c][2], accr[c][3]);
      *(uint2*)(xr + o) = vr;
    }
  }
}

// ================= phase 2: per-bucket counting sort → CSR =================

__device__ void dev_ph2(int k, const int* __restrict__ ph1off,
                        const uint* __restrict__ ebuf,
                        int* __restrict__ csr_off, ushort* __restrict__ csr_src) {
  __shared__ int ccnt[256], coff[256], lcur[256], tmp[256];
  int t = threadIdx.x;
  int beg = ph1off[k * 256];
  int end = (k == 255) ? EE : ph1off[(k + 1) * 256];
  ccnt[t] = 0;
  lcur[t] = 0;
  __syncthreads();
  for (int e = beg + t; e < end; e += 256) {
    uint u = ebuf[e];
    atomicAdd(&ccnt[(u >> 16) & 255], 1);
  }
  __syncthreads();
  int s = ccnt[t];
  tmp[t] = s;
#pragma unroll
  for (int d = 1; d < 256; d <<= 1) {
    __syncthreads();
    int u = (t >= d) ? tmp[t - d] : 0;
    __syncthreads();
    tmp[t] += u;
  }
  __syncthreads();
  coff[t] = tmp[t] - s;
  csr_off[k * 256 + t] = beg + tmp[t] - s;
  if (k == 255 && t == 0) csr_off[NN] = EE;
  __syncthreads();
  for (int e = beg + t; e < end; e += 256) {
    uint u = ebuf[e];
    int j = (u >> 16) & 255;
    int pos = atomicAdd(&lcur[j], 1);
    csr_src[beg + coff[j] + pos] = (ushort)(u & 0xFFFFu);
  }
}

__global__ __launch_bounds__(256) void k_ph2_gemm1(
    const int* __restrict__ ph1off, const uint* __restrict__ ebuf,
    int* __restrict__ csr_off, ushort* __restrict__ csr_src,
    const float* __restrict__ x, const ushort* __restrict__ P1l,
    const ushort* __restrict__ P1r, ushort* __restrict__ xl,
    ushort* __restrict__ xr) {
  int b = blockIdx.x;
  if (b < PH2_B) dev_ph2(b, ph1off, ebuf, csr_off, csr_src);
  else dev_gemm<128, 128, 8, true>(b - PH2_B, x, P1l, P1r, xl, xr);
}

// ================= pools (all-wave, LDS reduce) / gemms (layers 2,3) ========

template <int FOUT>
__device__ void dev_pool(int g, const ushort* __restrict__ h,
                         const int* __restrict__ goff,
                         float* __restrict__ pooled, int colbase) {
  constexpr int PAIRS = FOUT / 2;     // 64 / 32
  constexpr int SUBS = 256 / PAIRS;   // 4 / 8
  __shared__ float red[SUBS][PAIRS][2];
  int t = threadIdx.x;
  int pi = t % PAIRS, sub = t / PAIRS;
  int n0 = goff[g], n1 = goff[g + 1];
  float a0 = 0.f, a1 = 0.f;
  const uint* h32 = (const uint*)h;
  for (int n = n0 + sub; n < n1; n += SUBS) {
    uint v = h32[(size_t)n * PAIRS + pi];
    a0 += lo_bf(v);
    a1 += hi_bf(v);
  }
  red[sub][pi][0] = a0;
  red[sub][pi][1] = a1;
  __syncthreads();
  if (sub == 0) {
    float s0 = 0.f, s1 = 0.f;
#pragma unroll
    for (int s = 0; s < SUBS; ++s) { s0 += red[s][pi][0]; s1 += red[s][pi][1]; }
    pooled[g * 256 + colbase + 2 * pi] = s0;
    pooled[g * 256 + colbase + 2 * pi + 1] = s1;
  }
}

__global__ __launch_bounds__(256) void k_pool1_gemm2(
    const ushort* __restrict__ h, const int* __restrict__ goff,
    float* __restrict__ pooled, const ushort* __restrict__ P2l,
    const ushort* __restrict__ P2r, ushort* __restrict__ xl,
    ushort* __restrict__ xr) {
  int b = blockIdx.x;
  if (b < POOL_B) dev_pool<128>(b, h, goff, pooled, 0);
  else dev_gemm<128, 64, 8, false>(b - POOL_B, h, P2l, P2r, xl, xr);
}

__global__ __launch_bounds__(256) void k_pool2_gemm3(
    const ushort* __restrict__ h, const int* __restrict__ goff,
    float* __restrict__ pooled, const ushort* __restrict__ P3l,
    const ushort* __restrict__ P3r, ushort* __restrict__ xl,
    ushort* __restrict__ xr) {
  int b = blockIdx.x;
  if (b < POOL_B) dev_pool<64>(b, h, goff, pooled, 128);
  else dev_gemm<64, 32, 8, false>(b - POOL_B, h, P3l, P3r, xl, xr);
}

// ================= edge aggregation: fixed-offset softmax, pipelined ========
// m is FIXED at the self-loop score (no running max): all batch updates are
// independent accumulations -> deep ILP across gather batches. Exponents are
// score - selfscore, bounded ~e^20 for BN-scale data; f32 range is ample.

template <int FOUT>
__global__ __launch_bounds__(256) void edge_kernel(
    const ushort* __restrict__ xl, const ushort* __restrict__ xr,
    const int* __restrict__ csr_off, const ushort* __restrict__ csr_src,
    const float* __restrict__ a, const float* __restrict__ b,
    const float* __restrict__ gam, const float* __restrict__ bet,
    ushort* __restrict__ hout) {
  constexpr int GROUP = FOUT / 8;   // 16 / 8 / 4
  constexpr int GPB = 256 / GROUP;
  int gid = blockIdx.x * GPB + threadIdx.x / GROUP;
  int lane = threadIdx.x % GROUP;
  const uint4* xl4 = (const uint4*)xl;

  f32x2 xrf[4];
  cvt8p(((const uint4*)xr)[(size_t)gid * GROUP + lane], xrf);
  f32x2 av[4];
  {
    float4 a0 = ((const float4*)a)[lane * 2], a1 = ((const float4*)a)[lane * 2 + 1];
    av[0] = (f32x2){a0.x, a0.y}; av[1] = (f32x2){a0.z, a0.w};
    av[2] = (f32x2){a1.x, a1.y}; av[3] = (f32x2){a1.z, a1.w};
  }

  // self loop: fixes the exponent offset m and seeds den=1, acc=xs
  f32x2 xs[4];
  cvt8p(xl4[(size_t)gid * GROUP + lane], xs);
  f32x2 q = (f32x2){0.f, 0.f};
#pragma unroll
  for (int j = 0; j < 4; ++j) {
    f32x2 z = xs[j] + xrf[j];
    q += __builtin_elementwise_max(z, z * 0.2f) * av[j];
  }
  float m = q.x + q.y;
#pragma unroll
  for (int wd = GROUP >> 1; wd >= 1; wd >>= 1) m += __shfl_xor(m, wd);
  float den = 1.f;
  f32x2 acc[4];
#pragma unroll
  for (int j = 0; j < 4; ++j) acc[j] = xs[j];

  int beg = csr_off[gid], end = csr_off[gid + 1];
  // pipelined batches of 4; tail edges masked via sc=-inf (p=0). csr_src has
  // +8 slack so over-reads are memory-safe; gathered rows are finite bf16.
  uint4 cv0 = {0, 0, 0, 0}, cv1 = cv0, cv2 = cv0, cv3 = cv0;
  if (beg < end) {
    int s0 = csr_src[beg], s1 = csr_src[beg + 1];
    int s2 = csr_src[beg + 2], s3 = csr_src[beg + 3];
    cv0 = xl4[(size_t)s0 * GROUP + lane];
    cv1 = xl4[(size_t)s1 * GROUP + lane];
    cv2 = xl4[(size_t)s2 * GROUP + lane];
    cv3 = xl4[(size_t)s3 * GROUP + lane];
  }
  for (int i = beg; i < end; i += 4) {
    uint4 nv0 = cv0, nv1 = cv1, nv2 = cv2, nv3 = cv3;
    int ip = i + 4;
    if (ip < end) {                      // issue next batch before consuming
      int s0 = csr_src[ip], s1 = csr_src[ip + 1];
      int s2 = csr_src[ip + 2], s3 = csr_src[ip + 3];
      nv0 = xl4[(size_t)s0 * GROUP + lane];
      nv1 = xl4[(size_t)s1 * GROUP + lane];
      nv2 = xl4[(size_t)s2 * GROUP + lane];
      nv3 = xl4[(size_t)s3 * GROUP + lane];
    }
    f32x2 x0[4], x1[4], x2[4], x3[4];
    cvt8p(cv0, x0); cvt8p(cv1, x1); cvt8p(cv2, x2); cvt8p(cv3, x3);
    f32x2 q0 = {0.f, 0.f}, q1 = {0.f, 0.f}, q2 = {0.f, 0.f}, q3 = {0.f, 0.f};
#pragma unroll
    for (int j = 0; j < 4; ++j) {
      f32x2 z0 = x0[j] + xrf[j];
      f32x2 z1 = x1[j] + xrf[j];
      f32x2 z2 = x2[j] + xrf[j];
      f32x2 z3 = x3[j] + xrf[j];
      q0 += __builtin_elementwise_max(z0, z0 * 0.2f) * av[j];
      q1 += __builtin_elementwise_max(z1, z1 * 0.2f) * av[j];
      q2 += __builtin_elementwise_max(z2, z2 * 0.2f) * av[j];
      q3 += __builtin_elementwise_max(z3, z3 * 0.2f) * av[j];
    }
    float sc0 = q0.x + q0.y, sc1 = q1.x + q1.y;
    float sc2 = q2.x + q2.y, sc3 = q3.x + q3.y;
    int rem = end - i;                   // >= 1, group-uniform
    if (rem < 4) {
      if (rem < 2) sc1 = -INFINITY;
      if (rem < 3) sc2 = -INFINITY;
      sc3 = -INFINITY;
    }
#pragma unroll
    for (int wd = GROUP >> 1; wd >= 1; wd >>= 1) {
      sc0 += __shfl_xor(sc0, wd);
      sc1 += __shfl_xor(sc1, wd);
      sc2 += __shfl_xor(sc2, wd);
      sc3 += __shfl_xor(sc3, wd);
    }
    float p0 = __expf(sc0 - m), p1 = __expf(sc1 - m);
    float p2 = __expf(sc2 - m), p3 = __expf(sc3 - m);
    den += p0 + p1 + p2 + p3;
#pragma unroll
    for (int j = 0; j < 4; ++j)
      acc[j] += x0[j] * p0 + x1[j] * p1 + x2[j] * p2 + x3[j] * p3;
    cv0 = nv0; cv1 = nv1; cv2 = nv2; cv3 = nv3;
  }

  float inv = 1.f / den;
  float4 b0 = ((const float4*)b)[lane * 2], b1 = ((const float4*)b)[lane * 2 + 1];
  float4 g0 = ((const float4*)gam)[lane * 2], g1 = ((const float4*)gam)[lane * 2 + 1];
  float4 e0 = ((const float4*)bet)[lane * 2], e1 = ((const float4*)bet)[lane * 2 + 1];
  f32x2 bb[4] = {{b0.x, b0.y}, {b0.z, b0.w}, {b1.x, b1.y}, {b1.z, b1.w}};
  f32x2 gg[4] = {{g0.x, g0.y}, {g0.z, g0.w}, {g1.x, g1.y}, {g1.z, g1.w}};
  f32x2 ee[4] = {{e0.x, e0.y}, {e0.z, e0.w}, {e1.x, e1.y}, {e1.z, e1.w}};
  f32x2 o[4];
#pragma unroll
  for (int j = 0; j < 4; ++j) {
    f32x2 r = acc[j] * inv + bb[j];
    r = __builtin_elementwise_max(r, (f32x2){0.f, 0.f});
    o[j] = r * (gg[j] * BNS) + ee[j];
  }
  uint4 pv;
  pv.x = pack_bf2(o[0].x, o[0].y); pv.y = pack_bf2(o[1].x, o[1].y);
  pv.z = pack_bf2(o[2].x, o[2].y); pv.w = pack_bf2(o[3].x, o[3].y);
  ((uint4*)hout)[(size_t)gid * GROUP + lane] = pv;
}

// ================= MLP head (pool3/pool4 fused in) =================

__global__ __launch_bounds__(128) void mlp_kernel(
    const ushort* __restrict__ h3, const int* __restrict__ goff,
    const float* __restrict__ pooled, const float* __restrict__ W1,
    const float* __restrict__ b1, const float* __restrict__ g5,
    const float* __restrict__ be5, const float* __restrict__ W2,
    const float* __restrict__ b2, float* __restrict__ out) {
  __shared__ float p[256];
  __shared__ float ps[8][16][2];
  __shared__ float hid[128];
  __shared__ float lg[16];
  int g = blockIdx.x, t = threadIdx.x;
  int n0 = goff[g], n1 = goff[g + 1];
  p[t] = pooled[g * 256 + t];
  if (t < 64) p[128 + t] = pooled[g * 256 + 128 + t];
  {
    int sub = t >> 4, pi = t & 15;
    float a0 = 0.f, a1 = 0.f;
    const uint* h32 = (const uint*)h3;
    for (int n = n0 + sub; n < n1; n += 8) {
      uint v = h32[(size_t)n * 16 + pi];
      a0 += lo_bf(v);
      a1 += hi_bf(v);
    }
    ps[sub][pi][0] = a0;
    ps[sub][pi][1] = a1;
  }
  __syncthreads();
  if (t < 16) {
    float s0 = 0.f, s1 = 0.f;
#pragma unroll
    for (int s = 0; s < 8; ++s) { s0 += ps[s][t][0]; s1 += ps[s][t][1]; }
    p[192 + 2 * t] = s0; p[193 + 2 * t] = s1;   // p3
    p[224 + 2 * t] = s0; p[225 + 2 * t] = s1;   // p4 (= p3, reference bug)
  }
  __syncthreads();
  float acc = b1[t];
  for (int k = 0; k < 256; ++k) acc = fmaf(p[k], W1[k * 128 + t], acc);
  acc = fmaxf(acc, 0.f) * (g5[t] * BNS) + be5[t];
  hid[t] = acc;
  __syncthreads();
  if (t < 16) {
    float l = b2[t];
    for (int k = 0; k < 128; ++k) l = fmaf(hid[k], W2[k * 16 + t], l);
    lg[t] = l;
  }
  __syncthreads();
  if (t < 16) {
    float l = lg[t];
    float m = lg[0];
    for (int k = 1; k < 16; ++k) m = fmaxf(m, lg[k]);
    float se = 0.f;
    for (int k = 0; k < 16; ++k) se += __expf(lg[k] - m);
    out[g * 16 + t] = 1.f / (1.f + __expf(-l));       // sigmoid
    out[NG * 16 + g * 16 + t] = l - m - __logf(se);   // log_softmax
  }
}

// ================= launch =================

extern "C" void kernel_launch(void* const* d_in, const int* in_sizes, int n_in,
                              void* d_out, int out_size, void* d_ws, size_t ws_size,
                              hipStream_t stream) {
  const float* x = (const float*)d_in[0];
  const int* ei = (const int*)d_in[1];
  const int* batch = (const int*)d_in[2];
  const float* Wl1 = (const float*)d_in[4];
  const float* Wr1 = (const float*)d_in[5];
  const float* a1 = (const float*)d_in[6];
  const float* b1 = (const float*)d_in[7];
  const float* g1 = (const float*)d_in[8];
  const float* be1 = (const float*)d_in[9];
  const float* Wl2 = (const float*)d_in[10];
  const float* Wr2 = (const float*)d_in[11];
  const float* a2 = (const float*)d_in[12];
  const float* b2 = (const float*)d_in[13];
  const float* g2 = (const float*)d_in[14];
  const float* be2 = (const float*)d_in[15];
  const float* Wl3 = (const float*)d_in[16];
  const float* Wr3 = (const float*)d_in[17];
  const float* a3 = (const float*)d_in[18];
  const float* b3 = (const float*)d_in[19];
  const float* g3 = (const float*)d_in[20];
  const float* be3 = (const float*)d_in[21];
  // layer 4 (d_in[22..27]) is dead in the reference (h4 = h3) — skipped.
  const float* lin1_W = (const float*)d_in[28];
  const float* lin1_b = (const float*)d_in[29];
  const float* g5 = (const float*)d_in[30];
  const float* be5 = (const float*)d_in[31];
  const float* lin2_W = (const float*)d_in[32];
  const float* lin2_b = (const float*)d_in[33];
  float* out = (float*)d_out;

  // workspace carve (16B-aligned chunks)
  char* w = (char*)d_ws;
  ushort* xl = (ushort*)w;   w += (size_t)NN * 128 * 2;  // 16 MB
  ushort* xr = (ushort*)w;   w += (size_t)NN * 128 * 2;  // 16 MB
  ushort* h  = (ushort*)w;   w += (size_t)NN * 128 * 2;  // 16 MB
  uint* ebuf = (uint*)w;     w += (size_t)EE * 4;        // 4 MB
  int* ph1cnt = (int*)w;     w += (size_t)65536 * 4;     // 256 KB
  int* ph1off = (int*)w;     w += (size_t)(65536 + 16) * 4;
  int* csr_off = (int*)w;    w += (size_t)(NN + 4) * 4;
  ushort* csr_src = (ushort*)w; w += (size_t)(EE + 8) * 2;
  ushort* P1l = (ushort*)w;  w += 65536;
  ushort* P1r = (ushort*)w;  w += 65536;
  ushort* P2l = (ushort*)w;  w += 65536;
  ushort* P2r = (ushort*)w;  w += 65536;
  ushort* P3l = (ushort*)w;  w += 65536;
  ushort* P3r = (ushort*)w;  w += 65536;
  int* bsum = (int*)w;       w += 64 * 4;
  int* boff = (int*)w;       w += 64 * 4;
  int* goff = (int*)w;       w += (size_t)(NG + 4) * 4;
  float* pooled = (float*)w; w += (size_t)NG * 256 * 4;

  // bucket counts | weight pack | graph bounds
  k_ph1a_pack_gbound<<<K1_B, 256, 0, stream>>>(ei, ph1cnt, Wl1, Wr1, Wl2, Wr2,
                                               Wl3, Wr3, P1l, P1r, P2l, P2r,
                                               P3l, P3r, batch, goff);
  scan1_kernel<<<64, 256, 0, stream>>>(ph1cnt, bsum);
  scan2_kernel<<<1, 64, 0, stream>>>(bsum, boff);
  scan3_kernel<<<64, 256, 0, stream>>>(ph1cnt, boff, ph1off);

  // bucket scatter
  k_ph1b<<<256, 256, 0, stream>>>(ei, ph1off, ebuf);

  // counting sort | gemm layer1 (f32 in, packed W)
  k_ph2_gemm1<<<K2_B, 256, 0, stream>>>(ph1off, ebuf, csr_off, csr_src,
                                        x, P1l, P1r, xl, xr);

  edge_kernel<128><<<NN / 16, 256, 0, stream>>>(xl, xr, csr_off, csr_src,
                                                a1, b1, g1, be1, h);

  // pool1 | gemm layer2
  k_pool1_gemm2<<<POOL_B + 512, 256, 0, stream>>>(h, goff, pooled, P2l, P2r,
                                                  xl, xr);
  edge_kernel<64><<<NN / 32, 256, 0, stream>>>(xl, xr, csr_off, csr_src,
                                               a2, b2, g2, be2, h);

  // pool2 | gemm layer3
  k_pool2_gemm3<<<POOL_B + 256, 256, 0, stream>>>(h, goff, pooled, P3l, P3r,
                                                  xl, xr);
  edge_kernel<32><<<NN / 64, 256, 0, stream>>>(xl, xr, csr_off, csr_src,
                                               a3, b3, g3, be3, h);

  // MLP head (pool3/p4 fused)
  mlp_kernel<<<NG, 128, 0, stream>>>(h, goff, pooled, lin1_W, lin1_b, g5, be5,
                                     lin2_W, lin2_b, out);
}